// Round 2
// 1086.326 us; speedup vs baseline: 1.1248x; 1.1248x over previous
//
#include <hip/hip_runtime.h>
#include <hip/hip_bf16.h>
#include <stdint.h>

// SimTransformer — fp32 I/O. R9: R8's 3-term split qk_mfma + narrow-band fp32
// borderline verify (R8 failed absmax 0.109 vs 0.108: split-only decisions
// widened the threshold-flip set). cs = hi*hi' + lo*hi' + hi*lo' (3 MFMAs);
// worst-case |cs - cs_f64| <= ~1.5e-5, so BAND=2.5e-4 (17x bound) is safe:
//   cs > 0.1+BAND  -> accept;  cs <= 0.1-BAND -> reject;
//   in-band        -> wave-parallel fp64-accumulated dot over fp32 qn rows
//                     (cast err 1.2e-7 vs proven fp64 gold).
// ~14 in-band pairs per 128x128 chunk (window 5e-4) -> ~10us total verify.
// Workspace: fp64 qtmp dies after norm_q; idxs+vals (CAP2=512) recycle its
// 64 MiB exactly; counts shrink to uint16; total == proven 151,060,480 B.

typedef __bf16 bf16;
typedef __bf16 bf16x8 __attribute__((ext_vector_type(8)));
typedef float f4 __attribute__((ext_vector_type(4)));

#define CAP2 512     // per-row per-m-half list cap (mean ~25/half)
#define BAND 2.5e-4f // borderline band around 0.1 (worst-case err ~1.5e-5)
#define BCAPC 512    // borderline pairs per 128-m chunk (mean ~14)

// ---------------------------------------------------------------------------
// K1: Q[n,e] = sum_d X[n,d]*W[e,d] in fp64. 64x64 tile, 256 thr (proven).
// ---------------------------------------------------------------------------
__global__ __launch_bounds__(256) void proj_f64(const float* __restrict__ X,
                                                const float* __restrict__ W,
                                                double* __restrict__ Q) {
    __shared__ double As[64][66];
    __shared__ double Bs[64][66];
    const int t = threadIdx.x, tn = t >> 4, te = t & 15;
    const int n0 = blockIdx.x * 64, e0 = blockIdx.y * 64;
    double acc[4][4] = {};
    for (int p = 0; p < 8; ++p) {
        __syncthreads();
        for (int q = 0; q < 16; ++q) {
            int id = q * 256 + t, r = id >> 6, c = id & 63;
            As[r][c] = (double)X[(size_t)(n0 + r) * 512 + p * 64 + c];
            Bs[r][c] = (double)W[(size_t)(e0 + r) * 512 + p * 64 + c];
        }
        __syncthreads();
        for (int kk = 0; kk < 64; ++kk) {
            double av[4], bv[4];
            for (int i = 0; i < 4; ++i) av[i] = As[tn + 16 * i][kk];
            for (int j = 0; j < 4; ++j) bv[j] = Bs[te + 16 * j][kk];
            for (int i = 0; i < 4; ++i)
                for (int j = 0; j < 4; ++j) acc[i][j] += av[i] * bv[j];
        }
    }
    for (int i = 0; i < 4; ++i)
        for (int j = 0; j < 4; ++j)
            Q[(size_t)(n0 + tn + 16 * i) * 512 + e0 + te + 16 * j] = acc[i][j];
}

// ---------------------------------------------------------------------------
// K1b: VT[b][e][m] = (X Wv^T)[m,e], fp32 accum, bf16 out, LDS-transposed.
// ---------------------------------------------------------------------------
__global__ __launch_bounds__(256) void proj_v(const float* __restrict__ X,
                                              const float* __restrict__ W,
                                              bf16* __restrict__ VT) {
    __shared__ float As[64][132];
    __shared__ float Bs[64][132];
    __shared__ bf16 Tt[64][72];   // [e-local][m-local]
    const int t = threadIdx.x, tn = t >> 4, te = t & 15;
    const int n0 = blockIdx.x * 64, e0 = blockIdx.y * 64;
    f4 acc[4][4] = {};
    for (int p = 0; p < 4; ++p) {
        __syncthreads();
        for (int q = 0; q < 8; ++q) {
            int id = q * 256 + t, r = id >> 5, c = (id & 31) * 4;
            *(f4*)&As[r][c] = *(const f4*)&X[(size_t)(n0 + r) * 512 + p * 128 + c];
            *(f4*)&Bs[r][c] = *(const f4*)&W[(size_t)(e0 + r) * 512 + p * 128 + c];
        }
        __syncthreads();
        for (int kk = 0; kk < 32; ++kk) {
            f4 av[4], bv[4];
            for (int i = 0; i < 4; ++i) av[i] = *(const f4*)&As[tn + 16 * i][kk * 4];
            for (int j = 0; j < 4; ++j) bv[j] = *(const f4*)&Bs[te + 16 * j][kk * 4];
            for (int i = 0; i < 4; ++i)
                for (int j = 0; j < 4; ++j) acc[i][j] += av[i] * bv[j];
        }
    }
    for (int i = 0; i < 4; ++i)
        for (int j = 0; j < 4; ++j) {
            f4 a = acc[i][j];
            Tt[te + 16 * j][tn + 16 * i] = (bf16)((a.x + a.y) + (a.z + a.w));
        }
    __syncthreads();
    const int b = n0 >> 12, ml = n0 & 4095;
    for (int i2 = 0; i2 < 2; ++i2) {
        int id = i2 * 256 + t, er = id >> 3, g = (id & 7) * 8;
        *(bf16x8*)&VT[((size_t)b * 512 + e0 + er) * 4096 + ml + g] =
            *(bf16x8*)&Tt[er][g];
    }
}

// ---------------------------------------------------------------------------
// K2: wave-per-row fp64 normalize -> fp32 qn + bf16 hi + bf16 lo split.
// ---------------------------------------------------------------------------
__global__ __launch_bounds__(256) void norm_q(const double* __restrict__ Q,
                                              float* __restrict__ QF,
                                              bf16* __restrict__ QH,
                                              bf16* __restrict__ QL) {
    const int wave = threadIdx.x >> 6, lane = threadIdx.x & 63;
    const int row = blockIdx.x * 4 + wave;
    const double* q = Q + (size_t)row * 512;
    double x[8];
    double s = 0.0;
    for (int j = 0; j < 8; ++j) { x[j] = q[lane * 8 + j]; s += x[j] * x[j]; }
    for (int off = 1; off < 64; off <<= 1) s += __shfl_xor(s, off);
    double nm = fmax(sqrt(s), 1e-12);
    for (int j = 0; j < 8; ++j) {
        float qf = (float)(x[j] / nm);
        bf16 h = (bf16)qf;
        QF[(size_t)row * 512 + lane * 8 + j] = qf;
        QH[(size_t)row * 512 + lane * 8 + j] = h;
        QL[(size_t)row * 512 + lane * 8 + j] = (bf16)(qf - (float)h);
    }
}

// ---------------------------------------------------------------------------
// K3: 3-term split-bf16 MFMA cosine + inline narrow-band fp32 verify.
// grid 256, 512 thr. bid&7 -> (batch, m-half) pinned per XCD; bid>>3 -> n0.
// A(hi,lo) in regs, B(hi,lo) double-buffered LDS with early-issued loads.
// ---------------------------------------------------------------------------
__global__ __launch_bounds__(512) void qk_mfma(const float* __restrict__ QF,
                                               const bf16* __restrict__ QHB,
                                               const bf16* __restrict__ QLB,
                                               uint16_t* __restrict__ counts,
                                               uint16_t* __restrict__ idxs,
                                               bf16* __restrict__ vals) {
    __shared__ bf16 Bs[2][2][128][136];   // [buf][hi/lo][m-loc][k pad] 139 KB
    __shared__ int cnt[128];
    __shared__ int bcnt;
    __shared__ uint32_t blist[BCAPC];     // 2 KB  (total ~142 KB)

    const int t = threadIdx.x;
    const int wave = t >> 6, lane = t & 63;
    const int ln16 = lane & 15, hi4 = lane >> 4;
    const int grp = blockIdx.x & 7;            // one (batch,half) per XCD
    const int b = grp >> 1, half = grp & 1;
    const int n0 = (blockIdx.x >> 3) * 128;
    const size_t nb = (size_t)b * 4096;
    const float* qf = QF + nb * 512;
    const bf16* qh = QHB + nb * 512;
    const bf16* ql = QLB + nb * 512;
    const int mbase = half * 2048;

    // A fragments: row = n0 + wave*16 + ln16, slice s=k0i*4+kk -> k = s*32+hi4*8
    const size_t arow = (size_t)(n0 + wave * 16 + ln16) * 512;
    bf16x8 Ah[16], Al[16];
#pragma unroll
    for (int s = 0; s < 16; ++s) {
        const int off = s * 32 + hi4 * 8;
        Ah[s] = *(const bf16x8*)&qh[arow + off];
        Al[s] = *(const bf16x8*)&ql[arow + off];
    }

    if (t < 128) cnt[t] = 0;
    if (t == 0) bcnt = 0;

    // prologue: stage (chunk 0, k0 0) into buf 0
#pragma unroll
    for (int i = 0; i < 4; ++i) {
        int id = i * 512 + t, r = id >> 4, g = (id & 15) * 8;
        *(bf16x8*)&Bs[0][0][r][g] = *(const bf16x8*)&qh[(size_t)(mbase + r) * 512 + g];
        *(bf16x8*)&Bs[0][1][r][g] = *(const bf16x8*)&ql[(size_t)(mbase + r) * 512 + g];
    }
    __syncthreads();

    for (int ch = 0; ch < 16; ++ch) {
        const int mst = mbase + ch * 128;
        f4 S[8] = {};
#pragma unroll
        for (int k0i = 0; k0i < 4; ++k0i) {
            const int buf = k0i & 1;
            const bool last = (k0i == 3) && (ch == 15);
            const int nmst = (k0i < 3) ? mst : mst + 128;
            const int nk0 = (k0i < 3) ? (k0i + 1) * 128 : 0;
            bf16x8 Lh[4], Ll[4];
            if (!last) {                        // issue next-step loads EARLY
#pragma unroll
                for (int i = 0; i < 4; ++i) {
                    int id = i * 512 + t, r = id >> 4, g = (id & 15) * 8;
                    Lh[i] = *(const bf16x8*)&qh[(size_t)(nmst + r) * 512 + nk0 + g];
                    Ll[i] = *(const bf16x8*)&ql[(size_t)(nmst + r) * 512 + nk0 + g];
                }
            }
#pragma unroll
            for (int kk = 0; kk < 4; ++kk) {
                const int s = k0i * 4 + kk;
                const bf16x8 ah = Ah[s], al = Al[s];
#pragma unroll
                for (int tt = 0; tt < 8; ++tt) {
                    bf16x8 bh = *(const bf16x8*)&Bs[buf][0][tt * 16 + ln16][kk * 32 + hi4 * 8];
                    bf16x8 bl = *(const bf16x8*)&Bs[buf][1][tt * 16 + ln16][kk * 32 + hi4 * 8];
                    S[tt] = __builtin_amdgcn_mfma_f32_16x16x32_bf16(ah, bh, S[tt], 0, 0, 0);
                    S[tt] = __builtin_amdgcn_mfma_f32_16x16x32_bf16(al, bh, S[tt], 0, 0, 0);
                    S[tt] = __builtin_amdgcn_mfma_f32_16x16x32_bf16(ah, bl, S[tt], 0, 0, 0);
                }
            }
            if (k0i == 3) {                     // chunk complete: threshold
                const int rl = wave * 16 + hi4 * 4;
#pragma unroll
                for (int tt = 0; tt < 8; ++tt) {
                    const int m = mst + tt * 16 + ln16;
#pragma unroll
                    for (int i = 0; i < 4; ++i) {
                        float cs = S[tt][i];
                        int row = rl + i;
                        if (cs > 0.1f + BAND) {
                            int pos = atomicAdd(&cnt[row], 1);
                            if (pos < CAP2) {
                                size_t o = ((size_t)(nb + n0 + row) * 2 + half) * CAP2 + pos;
                                idxs[o] = (uint16_t)m;
                                vals[o] = (bf16)cs;
                            }
                        } else if (cs > 0.1f - BAND) {
                            int bp = atomicAdd(&bcnt, 1);
                            if (bp < BCAPC)
                                blist[bp] = ((uint32_t)row << 12) | (uint32_t)m;
                        }
                    }
                }
            }
            __syncthreads();           // Bs[buf^1] reads done; blist complete
            if (!last) {
#pragma unroll
                for (int i = 0; i < 4; ++i) {
                    int id = i * 512 + t, r = id >> 4, g = (id & 15) * 8;
                    *(bf16x8*)&Bs[buf ^ 1][0][r][g] = Lh[i];
                    *(bf16x8*)&Bs[buf ^ 1][1][r][g] = Ll[i];
                }
            }
            if (k0i == 3) {            // wave-parallel fp32/f64-acc verify
                int nbd = bcnt; if (nbd > BCAPC) nbd = BCAPC;
                for (int p = wave; p < nbd; p += 8) {
                    uint32_t pk = blist[p];
                    int row = (int)(pk >> 12), m = (int)(pk & 4095);
                    const float* qa = qf + (size_t)(n0 + row) * 512;
                    const float* qc = qf + (size_t)m * 512;
                    f4 a0 = *(const f4*)&qa[lane * 8];
                    f4 a1 = *(const f4*)&qa[lane * 8 + 4];
                    f4 c0 = *(const f4*)&qc[lane * 8];
                    f4 c1 = *(const f4*)&qc[lane * 8 + 4];
                    double s = (double)a0.x * c0.x + (double)a0.y * c0.y +
                               (double)a0.z * c0.z + (double)a0.w * c0.w +
                               (double)a1.x * c1.x + (double)a1.y * c1.y +
                               (double)a1.z * c1.z + (double)a1.w * c1.w;
                    for (int off = 1; off < 64; off <<= 1) s += __shfl_xor(s, off);
                    if (lane == 0 && s > 0.1) {
                        int pos = atomicAdd(&cnt[row], 1);
                        if (pos < CAP2) {
                            size_t o = ((size_t)(nb + n0 + row) * 2 + half) * CAP2 + pos;
                            idxs[o] = (uint16_t)m;
                            vals[o] = (bf16)(float)s;
                        }
                    }
                }
            }
            __syncthreads();           // staging writes visible; verify done
            if (k0i == 3 && t == 0) bcnt = 0;   // next appends are >=3 barriers away
        }
    }
    __syncthreads();
    if (t < 128) {
        int c = cnt[t];
        counts[(size_t)(nb + n0 + t) * 2 + half] = (uint16_t)(c > CAP2 ? CAP2 : c);
    }
}

// ---------------------------------------------------------------------------
// K4: MFMA PV + fused LayerNorm. grid 512 (4 b x 128 32-row tiles), 512 thr.
// Lists are per (row, m-half): sorted-chunk scan switches half at m0==2048.
// ---------------------------------------------------------------------------
__global__ __launch_bounds__(512) void pv_mfma(const bf16* __restrict__ VT,
                                               const uint16_t* __restrict__ counts,
                                               const uint16_t* __restrict__ idxs,
                                               const bf16* __restrict__ vals,
                                               const float* __restrict__ gamma,
                                               const float* __restrict__ beta,
                                               float* __restrict__ Out) {
    __shared__ bf16 Wsm[32][136];      //  8,704 B
    __shared__ bf16 Vts[128][136];     // 34,816 B
    __shared__ int cur[32];
    __shared__ float red[4][32][2];    //  1,024 B

    const int t = threadIdx.x;
    const int wave = t >> 6, lane = t & 63;
    const int ln16 = lane & 15, hi4 = lane >> 4;
    const int rg = wave & 1, et = wave >> 1;
    const int b = blockIdx.x >> 7;
    const int n0 = (blockIdx.x & 127) * 32;
    const size_t nb = (size_t)b * 4096;
    const bf16* vtb = VT + (size_t)b * 512 * 4096;

    int myc0 = 0, myc1 = 0;
    if (t < 32) {
        int c0 = (int)counts[(size_t)(nb + n0 + t) * 2 + 0];
        int c1 = (int)counts[(size_t)(nb + n0 + t) * 2 + 1];
        myc0 = c0 > CAP2 ? CAP2 : c0;
        myc1 = c1 > CAP2 ? CAP2 : c1;
        cur[t] = 0;
    }

    f4 O[8] = {};   // [cc*2+s]: rows rg*16+hi4*4+i, col cc*128+et*32+s*16+ln16

    for (int m0 = 0; m0 < 4096; m0 += 128) {
        __syncthreads();               // prev chunk's MFMA reads of Wsm done
        if (t < 32) {                  // row-owner: zero row + scatter entries
            uint32_t* wz = (uint32_t*)&Wsm[t][0];
            for (int j = 0; j < 68; ++j) wz[j] = 0;
            const int h = m0 >> 11;
            const size_t base = ((size_t)(nb + n0 + t) * 2 + h) * CAP2;
            const int myc = h ? myc1 : myc0;
            int cu = (m0 == 2048) ? 0 : cur[t];
            while (cu < myc) {
                int mi = (int)(idxs[base + cu] & 4095);
                if (mi >= m0 + 128) break;
                int lo = mi - m0;
                if (lo >= 0) Wsm[t][lo] = vals[base + cu];
                ++cu;
            }
            cur[t] = cu;
        }
        __syncthreads();               // W tile ready
        for (int cc = 0; cc < 4; ++cc) {
            for (int i = 0; i < 4; ++i) {
                int id = i * 512 + t, r = id >> 4, g = (id & 15) * 8;
                *(bf16x8*)&Vts[r][g] =
                    *(const bf16x8*)&vtb[(size_t)(cc * 128 + r) * 4096 + m0 + g];
            }
            __syncthreads();           // Vts ready
            for (int kk = 0; kk < 4; ++kk) {
                bf16x8 aw = *(const bf16x8*)&Wsm[rg * 16 + ln16][kk * 32 + hi4 * 8];
                for (int s2 = 0; s2 < 2; ++s2) {
                    bf16x8 bv = *(const bf16x8*)&Vts[et * 32 + s2 * 16 + ln16][kk * 32 + hi4 * 8];
                    O[cc * 2 + s2] = __builtin_amdgcn_mfma_f32_16x16x32_bf16(
                        aw, bv, O[cc * 2 + s2], 0, 0, 0);
                }
            }
            __syncthreads();           // Vts safe to overwrite
        }
    }

    // ---- fused LayerNorm over 512 cols ----
    const int rloc = rg * 16 + hi4 * 4;
    float ps[4] = {0, 0, 0, 0}, pq[4] = {0, 0, 0, 0};
    for (int idx = 0; idx < 8; ++idx)
        for (int i = 0; i < 4; ++i) {
            float v = O[idx][i]; ps[i] += v; pq[i] += v * v;
        }
    for (int off = 1; off < 16; off <<= 1)
        for (int i = 0; i < 4; ++i) {
            ps[i] += __shfl_xor(ps[i], off);
            pq[i] += __shfl_xor(pq[i], off);
        }
    if (ln16 == 0)
        for (int i = 0; i < 4; ++i) {
            red[et][rloc + i][0] = ps[i];
            red[et][rloc + i][1] = pq[i];
        }
    __syncthreads();
    float mu[4], rs[4];
    for (int i = 0; i < 4; ++i) {
        float s = red[0][rloc + i][0] + red[1][rloc + i][0] +
                  red[2][rloc + i][0] + red[3][rloc + i][0];
        float q2 = red[0][rloc + i][1] + red[1][rloc + i][1] +
                   red[2][rloc + i][1] + red[3][rloc + i][1];
        mu[i] = s * (1.0f / 512.0f);
        float var = q2 * (1.0f / 512.0f) - mu[i] * mu[i];
        rs[i] = rsqrtf(var + 1e-5f);
    }
    for (int cc = 0; cc < 4; ++cc)
        for (int s2 = 0; s2 < 2; ++s2) {
            int col = cc * 128 + et * 32 + s2 * 16 + ln16;
            float g = gamma[col], be = beta[col];
            for (int i = 0; i < 4; ++i) {
                float y = (O[cc * 2 + s2][i] - mu[i]) * rs[i] * g + be;
                Out[(nb + n0 + rloc + i) * 512 + col] = y;
            }
        }
}

// ---------------------------------------------------------------------------
extern "C" void kernel_launch(void* const* d_in, const int* in_sizes, int n_in,
                              void* d_out, int out_size, void* d_ws, size_t ws_size,
                              hipStream_t stream) {
    const float* x     = (const float*)d_in[0];
    const float* wqk   = (const float*)d_in[1];
    const float* wv    = (const float*)d_in[2];
    const float* gamma = (const float*)d_in[3];
    const float* beta  = (const float*)d_in[4];
    float* out = (float*)d_out;

    char* ws = (char*)d_ws;
    // fp64 qtmp [0, 67,108,864) dies after norm_q; idxs+vals recycle it EXACTLY.
    uint16_t* idxs   = (uint16_t*)ws;                        // 33,554,432 B
    bf16*     vals   = (bf16*)(ws + 33554432);               // 33,554,432 B -> 67,108,864
    float*    qn32   = (float*)(ws + 67108864);              // 33,554,432 B -> 100,663,296
    bf16*     qh     = (bf16*)(ws + 100663296);              // 16,777,216 B -> 117,440,512
    bf16*     qlo    = (bf16*)(ws + 117440512);              // 16,777,216 B -> 134,217,728
    bf16*     vt     = (bf16*)(ws + 134217728);              // 16,777,216 B -> 150,994,944
    uint16_t* counts = (uint16_t*)(ws + 150994944);          //     65,536 B -> 151,060,480
    double*   qtmp   = (double*)ws;                          // TEMP, dies after norm_q
    const size_t need = 151060480;  // == R2-proven ws_size lower bound
    if (ws_size < need) return;

    proj_f64<<<dim3(256, 8), 256, 0, stream>>>(x, wqk, qtmp);
    proj_v<<<dim3(256, 8), 256, 0, stream>>>(x, wv, vt);
    norm_q<<<4096, 256, 0, stream>>>(qtmp, qn32, qh, qlo);
    qk_mfma<<<256, 512, 0, stream>>>(qn32, qh, qlo, counts, idxs, vals);
    pv_mfma<<<512, 512, 0, stream>>>(vt, counts, idxs, vals, gamma, beta, out);
}

// Round 3
// 890.048 us; speedup vs baseline: 1.3729x; 1.2205x over previous
//
#include <hip/hip_runtime.h>
#include <hip/hip_bf16.h>
#include <stdint.h>

// SimTransformer — fp32 I/O. R10: pv_mfma rewritten (R9's was LDS-BW-bound
// with 8-way bank conflicts: model 360us == measured 361us).
// New pv: 64-row blocks (grid 256, 1/CU), 32x32x16 MFMA with 2n x 2e register
// tiles per wave (1 ds_read_b128 per 32-KFLOP MFMA), full Vts[512][128]
// staged once per 128-m chunk via T14 reg-staging, XOR-16 slot swizzle
// (slot ^= row&15) -> 2-way (free) LDS reads, owner-scatter with 16-entry
// register prefetch window. qk_mfma/proj/norm unchanged from R9 (proven).

typedef __bf16 bf16;
typedef __bf16 bf16x8 __attribute__((ext_vector_type(8)));
typedef unsigned short u16x8 __attribute__((ext_vector_type(8)));
typedef float f4 __attribute__((ext_vector_type(4)));
typedef float f16v __attribute__((ext_vector_type(16)));

#define CAP2 512     // per-row per-m-half list cap (mean ~25/half)
#define BAND 2.5e-4f // borderline band around 0.1 (worst-case err ~1.5e-5)
#define BCAPC 512    // borderline pairs per 128-m chunk (mean ~14)

// ---------------------------------------------------------------------------
// K1: Q[n,e] = sum_d X[n,d]*W[e,d] in fp64. 64x64 tile, 256 thr (proven).
// ---------------------------------------------------------------------------
__global__ __launch_bounds__(256) void proj_f64(const float* __restrict__ X,
                                                const float* __restrict__ W,
                                                double* __restrict__ Q) {
    __shared__ double As[64][66];
    __shared__ double Bs[64][66];
    const int t = threadIdx.x, tn = t >> 4, te = t & 15;
    const int n0 = blockIdx.x * 64, e0 = blockIdx.y * 64;
    double acc[4][4] = {};
    for (int p = 0; p < 8; ++p) {
        __syncthreads();
        for (int q = 0; q < 16; ++q) {
            int id = q * 256 + t, r = id >> 6, c = id & 63;
            As[r][c] = (double)X[(size_t)(n0 + r) * 512 + p * 64 + c];
            Bs[r][c] = (double)W[(size_t)(e0 + r) * 512 + p * 64 + c];
        }
        __syncthreads();
        for (int kk = 0; kk < 64; ++kk) {
            double av[4], bv[4];
            for (int i = 0; i < 4; ++i) av[i] = As[tn + 16 * i][kk];
            for (int j = 0; j < 4; ++j) bv[j] = Bs[te + 16 * j][kk];
            for (int i = 0; i < 4; ++i)
                for (int j = 0; j < 4; ++j) acc[i][j] += av[i] * bv[j];
        }
    }
    for (int i = 0; i < 4; ++i)
        for (int j = 0; j < 4; ++j)
            Q[(size_t)(n0 + tn + 16 * i) * 512 + e0 + te + 16 * j] = acc[i][j];
}

// ---------------------------------------------------------------------------
// K1b: VT[b][e][m] = (X Wv^T)[m,e], fp32 accum, bf16 out, LDS-transposed.
// ---------------------------------------------------------------------------
__global__ __launch_bounds__(256) void proj_v(const float* __restrict__ X,
                                              const float* __restrict__ W,
                                              bf16* __restrict__ VT) {
    __shared__ float As[64][132];
    __shared__ float Bs[64][132];
    __shared__ bf16 Tt[64][72];   // [e-local][m-local]
    const int t = threadIdx.x, tn = t >> 4, te = t & 15;
    const int n0 = blockIdx.x * 64, e0 = blockIdx.y * 64;
    f4 acc[4][4] = {};
    for (int p = 0; p < 4; ++p) {
        __syncthreads();
        for (int q = 0; q < 8; ++q) {
            int id = q * 256 + t, r = id >> 5, c = (id & 31) * 4;
            *(f4*)&As[r][c] = *(const f4*)&X[(size_t)(n0 + r) * 512 + p * 128 + c];
            *(f4*)&Bs[r][c] = *(const f4*)&W[(size_t)(e0 + r) * 512 + p * 128 + c];
        }
        __syncthreads();
        for (int kk = 0; kk < 32; ++kk) {
            f4 av[4], bv[4];
            for (int i = 0; i < 4; ++i) av[i] = *(const f4*)&As[tn + 16 * i][kk * 4];
            for (int j = 0; j < 4; ++j) bv[j] = *(const f4*)&Bs[te + 16 * j][kk * 4];
            for (int i = 0; i < 4; ++i)
                for (int j = 0; j < 4; ++j) acc[i][j] += av[i] * bv[j];
        }
    }
    for (int i = 0; i < 4; ++i)
        for (int j = 0; j < 4; ++j) {
            f4 a = acc[i][j];
            Tt[te + 16 * j][tn + 16 * i] = (bf16)((a.x + a.y) + (a.z + a.w));
        }
    __syncthreads();
    const int b = n0 >> 12, ml = n0 & 4095;
    for (int i2 = 0; i2 < 2; ++i2) {
        int id = i2 * 256 + t, er = id >> 3, g = (id & 7) * 8;
        *(bf16x8*)&VT[((size_t)b * 512 + e0 + er) * 4096 + ml + g] =
            *(bf16x8*)&Tt[er][g];
    }
}

// ---------------------------------------------------------------------------
// K2: wave-per-row fp64 normalize -> fp32 qn + bf16 hi + bf16 lo split.
// ---------------------------------------------------------------------------
__global__ __launch_bounds__(256) void norm_q(const double* __restrict__ Q,
                                              float* __restrict__ QF,
                                              bf16* __restrict__ QH,
                                              bf16* __restrict__ QL) {
    const int wave = threadIdx.x >> 6, lane = threadIdx.x & 63;
    const int row = blockIdx.x * 4 + wave;
    const double* q = Q + (size_t)row * 512;
    double x[8];
    double s = 0.0;
    for (int j = 0; j < 8; ++j) { x[j] = q[lane * 8 + j]; s += x[j] * x[j]; }
    for (int off = 1; off < 64; off <<= 1) s += __shfl_xor(s, off);
    double nm = fmax(sqrt(s), 1e-12);
    for (int j = 0; j < 8; ++j) {
        float qf = (float)(x[j] / nm);
        bf16 h = (bf16)qf;
        QF[(size_t)row * 512 + lane * 8 + j] = qf;
        QH[(size_t)row * 512 + lane * 8 + j] = h;
        QL[(size_t)row * 512 + lane * 8 + j] = (bf16)(qf - (float)h);
    }
}

// ---------------------------------------------------------------------------
// K3: 3-term split-bf16 MFMA cosine + inline narrow-band fp32 verify.
// grid 256, 512 thr. (unchanged from R9 — proven)
// ---------------------------------------------------------------------------
__global__ __launch_bounds__(512) void qk_mfma(const float* __restrict__ QF,
                                               const bf16* __restrict__ QHB,
                                               const bf16* __restrict__ QLB,
                                               uint16_t* __restrict__ counts,
                                               uint16_t* __restrict__ idxs,
                                               bf16* __restrict__ vals) {
    __shared__ bf16 Bs[2][2][128][136];   // [buf][hi/lo][m-loc][k pad] 139 KB
    __shared__ int cnt[128];
    __shared__ int bcnt;
    __shared__ uint32_t blist[BCAPC];     // 2 KB  (total ~142 KB)

    const int t = threadIdx.x;
    const int wave = t >> 6, lane = t & 63;
    const int ln16 = lane & 15, hi4 = lane >> 4;
    const int grp = blockIdx.x & 7;            // one (batch,half) per XCD
    const int b = grp >> 1, half = grp & 1;
    const int n0 = (blockIdx.x >> 3) * 128;
    const size_t nb = (size_t)b * 4096;
    const float* qf = QF + nb * 512;
    const bf16* qh = QHB + nb * 512;
    const bf16* ql = QLB + nb * 512;
    const int mbase = half * 2048;

    const size_t arow = (size_t)(n0 + wave * 16 + ln16) * 512;
    bf16x8 Ah[16], Al[16];
#pragma unroll
    for (int s = 0; s < 16; ++s) {
        const int off = s * 32 + hi4 * 8;
        Ah[s] = *(const bf16x8*)&qh[arow + off];
        Al[s] = *(const bf16x8*)&ql[arow + off];
    }

    if (t < 128) cnt[t] = 0;
    if (t == 0) bcnt = 0;

#pragma unroll
    for (int i = 0; i < 4; ++i) {
        int id = i * 512 + t, r = id >> 4, g = (id & 15) * 8;
        *(bf16x8*)&Bs[0][0][r][g] = *(const bf16x8*)&qh[(size_t)(mbase + r) * 512 + g];
        *(bf16x8*)&Bs[0][1][r][g] = *(const bf16x8*)&ql[(size_t)(mbase + r) * 512 + g];
    }
    __syncthreads();

    for (int ch = 0; ch < 16; ++ch) {
        const int mst = mbase + ch * 128;
        f4 S[8] = {};
#pragma unroll
        for (int k0i = 0; k0i < 4; ++k0i) {
            const int buf = k0i & 1;
            const bool last = (k0i == 3) && (ch == 15);
            const int nmst = (k0i < 3) ? mst : mst + 128;
            const int nk0 = (k0i < 3) ? (k0i + 1) * 128 : 0;
            bf16x8 Lh[4], Ll[4];
            if (!last) {                        // issue next-step loads EARLY
#pragma unroll
                for (int i = 0; i < 4; ++i) {
                    int id = i * 512 + t, r = id >> 4, g = (id & 15) * 8;
                    Lh[i] = *(const bf16x8*)&qh[(size_t)(nmst + r) * 512 + nk0 + g];
                    Ll[i] = *(const bf16x8*)&ql[(size_t)(nmst + r) * 512 + nk0 + g];
                }
            }
#pragma unroll
            for (int kk = 0; kk < 4; ++kk) {
                const int s = k0i * 4 + kk;
                const bf16x8 ah = Ah[s], al = Al[s];
#pragma unroll
                for (int tt = 0; tt < 8; ++tt) {
                    bf16x8 bh = *(const bf16x8*)&Bs[buf][0][tt * 16 + ln16][kk * 32 + hi4 * 8];
                    bf16x8 bl = *(const bf16x8*)&Bs[buf][1][tt * 16 + ln16][kk * 32 + hi4 * 8];
                    S[tt] = __builtin_amdgcn_mfma_f32_16x16x32_bf16(ah, bh, S[tt], 0, 0, 0);
                    S[tt] = __builtin_amdgcn_mfma_f32_16x16x32_bf16(al, bh, S[tt], 0, 0, 0);
                    S[tt] = __builtin_amdgcn_mfma_f32_16x16x32_bf16(ah, bl, S[tt], 0, 0, 0);
                }
            }
            if (k0i == 3) {                     // chunk complete: threshold
                const int rl = wave * 16 + hi4 * 4;
#pragma unroll
                for (int tt = 0; tt < 8; ++tt) {
                    const int m = mst + tt * 16 + ln16;
#pragma unroll
                    for (int i = 0; i < 4; ++i) {
                        float cs = S[tt][i];
                        int row = rl + i;
                        if (cs > 0.1f + BAND) {
                            int pos = atomicAdd(&cnt[row], 1);
                            if (pos < CAP2) {
                                size_t o = ((size_t)(nb + n0 + row) * 2 + half) * CAP2 + pos;
                                idxs[o] = (uint16_t)m;
                                vals[o] = (bf16)cs;
                            }
                        } else if (cs > 0.1f - BAND) {
                            int bp = atomicAdd(&bcnt, 1);
                            if (bp < BCAPC)
                                blist[bp] = ((uint32_t)row << 12) | (uint32_t)m;
                        }
                    }
                }
            }
            __syncthreads();           // Bs[buf^1] reads done; blist complete
            if (!last) {
#pragma unroll
                for (int i = 0; i < 4; ++i) {
                    int id = i * 512 + t, r = id >> 4, g = (id & 15) * 8;
                    *(bf16x8*)&Bs[buf ^ 1][0][r][g] = Lh[i];
                    *(bf16x8*)&Bs[buf ^ 1][1][r][g] = Ll[i];
                }
            }
            if (k0i == 3) {            // wave-parallel fp32/f64-acc verify
                int nbd = bcnt; if (nbd > BCAPC) nbd = BCAPC;
                for (int p = wave; p < nbd; p += 8) {
                    uint32_t pk = blist[p];
                    int row = (int)(pk >> 12), m = (int)(pk & 4095);
                    const float* qa = qf + (size_t)(n0 + row) * 512;
                    const float* qc = qf + (size_t)m * 512;
                    f4 a0 = *(const f4*)&qa[lane * 8];
                    f4 a1 = *(const f4*)&qa[lane * 8 + 4];
                    f4 c0 = *(const f4*)&qc[lane * 8];
                    f4 c1 = *(const f4*)&qc[lane * 8 + 4];
                    double s = (double)a0.x * c0.x + (double)a0.y * c0.y +
                               (double)a0.z * c0.z + (double)a0.w * c0.w +
                               (double)a1.x * c1.x + (double)a1.y * c1.y +
                               (double)a1.z * c1.z + (double)a1.w * c1.w;
                    for (int off = 1; off < 64; off <<= 1) s += __shfl_xor(s, off);
                    if (lane == 0 && s > 0.1) {
                        int pos = atomicAdd(&cnt[row], 1);
                        if (pos < CAP2) {
                            size_t o = ((size_t)(nb + n0 + row) * 2 + half) * CAP2 + pos;
                            idxs[o] = (uint16_t)m;
                            vals[o] = (bf16)(float)s;
                        }
                    }
                }
            }
            __syncthreads();           // staging writes visible; verify done
            if (k0i == 3 && t == 0) bcnt = 0;
        }
    }
    __syncthreads();
    if (t < 128) {
        int c = cnt[t];
        counts[(size_t)(nb + n0 + t) * 2 + half] = (uint16_t)(c > CAP2 ? CAP2 : c);
    }
}

// ---------------------------------------------------------------------------
// K4 (R10): 32x32x16-MFMA PV + fused LayerNorm. grid 256 (1 block/CU),
// 512 thr, 64 rows x 512 cols per block. Per 128-m chunk: Vts[512][128]
// reg-staged once (T14: loads issued before MFMA phase), Wsm[64][128]
// zero+scatter by row-owners with 16-entry register prefetch window.
// XOR-16 slot swizzle (slot ^= row&15) on both tiles -> 2-way (free) reads.
// Per wave: 2 n-tiles x 2 e-tiles of 32x32, 1 ds_read_b128 per MFMA.
// ---------------------------------------------------------------------------
__global__ __launch_bounds__(512, 2) void pv_mfma(const bf16* __restrict__ VT,
                                                  const uint16_t* __restrict__ counts,
                                                  const uint16_t* __restrict__ idxs,
                                                  const bf16* __restrict__ vals,
                                                  const float* __restrict__ gamma,
                                                  const float* __restrict__ beta,
                                                  float* __restrict__ Out) {
    __shared__ __align__(16) char smemraw[147456];   // Vts 128K + Wsm 16K
    bf16 (*Vts)[128] = (bf16(*)[128])smemraw;        // [512 e][128 m] swz
    bf16 (*Wsm)[128] = (bf16(*)[128])(smemraw + 131072); // [64 n][128 m] swz

    const int t = threadIdx.x;
    const int wave = t >> 6, lane = t & 63;
    const int l31 = lane & 31, l15 = lane & 15, g = lane >> 5;
    const int grp = blockIdx.x & 7;                  // XCD-pinned batch panel
    const int b = grp >> 1;
    const int n0 = ((blockIdx.x >> 3) + ((grp & 1) ? 32 : 0)) * 64;
    const size_t nb = (size_t)b * 4096;
    const bf16* vtb = VT + (size_t)b * 512 * 4096;

    // owner (t<64) list state
    int myc0 = 0, myc1 = 0, cu = 0, pb = 0;
    u16x8 pi0 = {}, pi1 = {};
    bf16x8 pv0 = {}, pv1 = {};
    size_t base0 = 0, base1 = 0;
    if (t < 64) {
        myc0 = (int)counts[(size_t)(nb + n0 + t) * 2 + 0];
        myc1 = (int)counts[(size_t)(nb + n0 + t) * 2 + 1];
        if (myc0 > CAP2) myc0 = CAP2;
        if (myc1 > CAP2) myc1 = CAP2;
        base0 = ((size_t)(nb + n0 + t) * 2 + 0) * CAP2;
        base1 = ((size_t)(nb + n0 + t) * 2 + 1) * CAP2;
        // prefetch window for chunk 0
        pi0 = *(const u16x8*)&idxs[base0];
        pi1 = *(const u16x8*)&idxs[base0 + 8];
        pv0 = *(const bf16x8*)&vals[base0];
        pv1 = *(const bf16x8*)&vals[base0 + 8];
    }

    // prologue: stage chunk 0 into regs
    bf16x8 L[16];
#pragma unroll
    for (int i = 0; i < 16; ++i) {
        int id = i * 512 + t, r = id >> 4, s = id & 15;
        L[i] = *(const bf16x8*)&vtb[(size_t)r * 4096 + s * 8];
    }

    f16v acc[2][2] = {};   // [nt][et]: rows nt*32+cdrow, cols wave*64+et*32+l31

    for (int ch = 0; ch < 32; ++ch) {
        __syncthreads();               // (a) prev MFMA done reading Vts/Wsm
        // ---- write staged V tile (swizzled slots) ----
#pragma unroll
        for (int i = 0; i < 16; ++i) {
            int id = i * 512 + t, r = id >> 4, s = id & 15;
            *(bf16x8*)&Vts[r][(s ^ (r & 15)) << 3] = L[i];
        }
        // ---- owner: zero + scatter W row for THIS chunk ----
        if (t < 64) {
            bf16 z0 = (bf16)0.0f;
            bf16x8 zv = {z0, z0, z0, z0, z0, z0, z0, z0};
#pragma unroll
            for (int sj = 0; sj < 16; ++sj) *(bf16x8*)&Wsm[t][sj * 8] = zv;
            if (ch == 16) cu = 0;
            const int m0l = ch * 128;
            const int myc = (ch >= 16) ? myc1 : myc0;
            const size_t base = (ch >= 16) ? base1 : base0;
            int end = cu;
#pragma unroll
            for (int j = 0; j < 16; ++j) {
                int pos = pb + j;
                int mi = (j < 8) ? (int)pi0[j] : (int)pi1[j - 8];
                bf16 vv = (j < 8) ? pv0[j] : pv1[j - 8];
                if (pos == end && pos < myc && mi < m0l + 128) {
                    int lo = mi - m0l;
                    Wsm[t][(((lo >> 3) ^ (t & 15)) << 3) | (lo & 7)] = vv;
                    end = pos + 1;
                }
            }
            if (end == pb + 16) {      // rare spill past prefetch window
                while (end < myc) {
                    int mi = (int)idxs[base + end];
                    if (mi >= m0l + 128) break;
                    int lo = mi - m0l;
                    Wsm[t][(((lo >> 3) ^ (t & 15)) << 3) | (lo & 7)] =
                        vals[base + end];
                    ++end;
                }
            }
            cu = end;
        }
        __syncthreads();               // (b) Vts/Wsm ready
        // ---- issue next chunk's loads + owner prefetch (T14) ----
        if (ch < 31) {
            const int mo = (ch + 1) * 128;
#pragma unroll
            for (int i = 0; i < 16; ++i) {
                int id = i * 512 + t, r = id >> 4, s = id & 15;
                L[i] = *(const bf16x8*)&vtb[(size_t)r * 4096 + mo + s * 8];
            }
            if (t < 64) {
                int ncu = (ch + 1 == 16) ? 0 : cu;
                const size_t nbase = (ch + 1 >= 16) ? base1 : base0;
                pb = ncu & ~7;
                pi0 = *(const u16x8*)&idxs[nbase + pb];
                pi1 = *(const u16x8*)&idxs[nbase + pb + 8];
                pv0 = *(const bf16x8*)&vals[nbase + pb];
                pv1 = *(const bf16x8*)&vals[nbase + pb + 8];
            }
        }
        // ---- MFMA: 8 k-slices x (2 nt x 2 et) ----
#pragma unroll
        for (int ks = 0; ks < 8; ++ks) {
            const int sw = (((ks * 2 + g) ^ l15) << 3);
            bf16x8 A0 = *(const bf16x8*)&Wsm[l31][sw];
            bf16x8 A1 = *(const bf16x8*)&Wsm[32 + l31][sw];
            bf16x8 B0 = *(const bf16x8*)&Vts[wave * 64 + l31][sw];
            bf16x8 B1 = *(const bf16x8*)&Vts[wave * 64 + 32 + l31][sw];
            acc[0][0] = __builtin_amdgcn_mfma_f32_32x32x16_bf16(A0, B0, acc[0][0], 0, 0, 0);
            acc[0][1] = __builtin_amdgcn_mfma_f32_32x32x16_bf16(A0, B1, acc[0][1], 0, 0, 0);
            acc[1][0] = __builtin_amdgcn_mfma_f32_32x32x16_bf16(A1, B0, acc[1][0], 0, 0, 0);
            acc[1][1] = __builtin_amdgcn_mfma_f32_32x32x16_bf16(A1, B1, acc[1][1], 0, 0, 0);
        }
    }

    // ---- fused LayerNorm over 512 cols (red/mrs alias dead Vts) ----
    __syncthreads();
    float* red = (float*)smemraw;            // [8][64][2]
    float* mrs = (float*)(smemraw + 4096);   // mu[64], rs[64]
#pragma unroll
    for (int nt = 0; nt < 2; ++nt)
#pragma unroll
        for (int r = 0; r < 16; ++r) {
            float v0 = acc[nt][0][r], v1 = acc[nt][1][r];
            float s = v0 + v1, q = v0 * v0 + v1 * v1;
            for (int off = 1; off < 32; off <<= 1) {
                s += __shfl_xor(s, off);
                q += __shfl_xor(q, off);
            }
            if (l31 == 0) {
                int nloc = nt * 32 + (r & 3) + 8 * (r >> 2) + 4 * g;
                red[(wave * 64 + nloc) * 2] = s;
                red[(wave * 64 + nloc) * 2 + 1] = q;
            }
        }
    __syncthreads();
    if (t < 64) {
        float s = 0.f, q = 0.f;
        for (int w2 = 0; w2 < 8; ++w2) {
            s += red[(w2 * 64 + t) * 2];
            q += red[(w2 * 64 + t) * 2 + 1];
        }
        float mu = s * (1.0f / 512.0f);
        float var = q * (1.0f / 512.0f) - mu * mu;
        mrs[t] = mu;
        mrs[64 + t] = rsqrtf(var + 1e-5f);
    }
    __syncthreads();
    const float g0 = gamma[wave * 64 + l31], g1 = gamma[wave * 64 + 32 + l31];
    const float b0 = beta[wave * 64 + l31], b1 = beta[wave * 64 + 32 + l31];
#pragma unroll
    for (int nt = 0; nt < 2; ++nt)
#pragma unroll
        for (int r = 0; r < 16; ++r) {
            int nloc = nt * 32 + (r & 3) + 8 * (r >> 2) + 4 * g;
            float mu = mrs[nloc], rs = mrs[64 + nloc];
            size_t ro = (nb + n0 + nloc) * 512;
            float y0 = (acc[nt][0][r] - mu) * rs * g0 + b0;
            float y1 = (acc[nt][1][r] - mu) * rs * g1 + b1;
            Out[ro + wave * 64 + l31] = y0;
            Out[ro + wave * 64 + 32 + l31] = y1;
        }
}

// ---------------------------------------------------------------------------
extern "C" void kernel_launch(void* const* d_in, const int* in_sizes, int n_in,
                              void* d_out, int out_size, void* d_ws, size_t ws_size,
                              hipStream_t stream) {
    const float* x     = (const float*)d_in[0];
    const float* wqk   = (const float*)d_in[1];
    const float* wv    = (const float*)d_in[2];
    const float* gamma = (const float*)d_in[3];
    const float* beta  = (const float*)d_in[4];
    float* out = (float*)d_out;

    char* ws = (char*)d_ws;
    // fp64 qtmp [0, 67,108,864) dies after norm_q; idxs+vals recycle it EXACTLY.
    uint16_t* idxs   = (uint16_t*)ws;                        // 33,554,432 B
    bf16*     vals   = (bf16*)(ws + 33554432);               // 33,554,432 B -> 67,108,864
    float*    qn32   = (float*)(ws + 67108864);              // 33,554,432 B -> 100,663,296
    bf16*     qh     = (bf16*)(ws + 100663296);              // 16,777,216 B -> 117,440,512
    bf16*     qlo    = (bf16*)(ws + 117440512);              // 16,777,216 B -> 134,217,728
    bf16*     vt     = (bf16*)(ws + 134217728);              // 16,777,216 B -> 150,994,944
    uint16_t* counts = (uint16_t*)(ws + 150994944);          //     65,536 B -> 151,060,480
    double*   qtmp   = (double*)ws;                          // TEMP, dies after norm_q
    const size_t need = 151060480;  // == R2-proven ws_size lower bound
    if (ws_size < need) return;

    proj_f64<<<dim3(256, 8), 256, 0, stream>>>(x, wqk, qtmp);
    proj_v<<<dim3(256, 8), 256, 0, stream>>>(x, wv, vt);
    norm_q<<<4096, 256, 0, stream>>>(qtmp, qn32, qh, qlo);
    qk_mfma<<<256, 512, 0, stream>>>(qn32, qh, qlo, counts, idxs, vals);
    pv_mfma<<<256, 512, 0, stream>>>(vt, counts, idxs, vals, gamma, beta, out);
}

// Round 4
// 746.138 us; speedup vs baseline: 1.6377x; 1.1929x over previous
//
#include <hip/hip_runtime.h>
#include <hip/hip_bf16.h>
#include <stdint.h>

// SimTransformer — fp32 I/O. R11: qk_mfma 3-term bf16 -> 1-term fp16.
// fp16 hi*hi' dot error sigma ~9e-6 (11-bit mantissa, unit vectors) ->
// BAND 2e-4 = 23 sigma, same safety class as R9's proven 2.5e-4 vs 1.5e-5.
// In-band pairs (~11/chunk) go to the R9-proven fp32-row/fp64-accum verify.
// New layout: 8 waves x (32 rows x 64 m), A fully in regs (128 VGPR), each
// B-read feeds 2 MFMAs -> 4x fewer LDS reads than R10's qk. XOR slot swizzle
// (c8 ^ row&15, rows 256B-aligned) replaces pad-136 -> uniform bank groups.
// pv_mfma / proj_f64 / proj_v byte-identical to R10 (proven, 890us total).

typedef __bf16 bf16;
typedef __bf16 bf16x8 __attribute__((ext_vector_type(8)));
typedef _Float16 f16;
typedef _Float16 f16x8 __attribute__((ext_vector_type(8)));
typedef unsigned short u16x8 __attribute__((ext_vector_type(8)));
typedef float f4 __attribute__((ext_vector_type(4)));
typedef float f16v __attribute__((ext_vector_type(16)));

#define CAP2 512     // per-row per-m-half list cap (mean ~25/half)
#define QBAND 2e-4f  // borderline band around 0.1 (fp16 1-term sigma ~9e-6)
#define BCAPC 512    // borderline pairs per 128-m chunk (mean ~11)

// ---------------------------------------------------------------------------
// K1: Q[n,e] = sum_d X[n,d]*W[e,d] in fp64. 64x64 tile, 256 thr (proven).
// ---------------------------------------------------------------------------
__global__ __launch_bounds__(256) void proj_f64(const float* __restrict__ X,
                                                const float* __restrict__ W,
                                                double* __restrict__ Q) {
    __shared__ double As[64][66];
    __shared__ double Bs[64][66];
    const int t = threadIdx.x, tn = t >> 4, te = t & 15;
    const int n0 = blockIdx.x * 64, e0 = blockIdx.y * 64;
    double acc[4][4] = {};
    for (int p = 0; p < 8; ++p) {
        __syncthreads();
        for (int q = 0; q < 16; ++q) {
            int id = q * 256 + t, r = id >> 6, c = id & 63;
            As[r][c] = (double)X[(size_t)(n0 + r) * 512 + p * 64 + c];
            Bs[r][c] = (double)W[(size_t)(e0 + r) * 512 + p * 64 + c];
        }
        __syncthreads();
        for (int kk = 0; kk < 64; ++kk) {
            double av[4], bv[4];
            for (int i = 0; i < 4; ++i) av[i] = As[tn + 16 * i][kk];
            for (int j = 0; j < 4; ++j) bv[j] = Bs[te + 16 * j][kk];
            for (int i = 0; i < 4; ++i)
                for (int j = 0; j < 4; ++j) acc[i][j] += av[i] * bv[j];
        }
    }
    for (int i = 0; i < 4; ++i)
        for (int j = 0; j < 4; ++j)
            Q[(size_t)(n0 + tn + 16 * i) * 512 + e0 + te + 16 * j] = acc[i][j];
}

// ---------------------------------------------------------------------------
// K1b: VT[b][e][m] = (X Wv^T)[m,e], fp32 accum, bf16 out, LDS-transposed.
// ---------------------------------------------------------------------------
__global__ __launch_bounds__(256) void proj_v(const float* __restrict__ X,
                                              const float* __restrict__ W,
                                              bf16* __restrict__ VT) {
    __shared__ float As[64][132];
    __shared__ float Bs[64][132];
    __shared__ bf16 Tt[64][72];   // [e-local][m-local]
    const int t = threadIdx.x, tn = t >> 4, te = t & 15;
    const int n0 = blockIdx.x * 64, e0 = blockIdx.y * 64;
    f4 acc[4][4] = {};
    for (int p = 0; p < 4; ++p) {
        __syncthreads();
        for (int q = 0; q < 8; ++q) {
            int id = q * 256 + t, r = id >> 5, c = (id & 31) * 4;
            *(f4*)&As[r][c] = *(const f4*)&X[(size_t)(n0 + r) * 512 + p * 128 + c];
            *(f4*)&Bs[r][c] = *(const f4*)&W[(size_t)(e0 + r) * 512 + p * 128 + c];
        }
        __syncthreads();
        for (int kk = 0; kk < 32; ++kk) {
            f4 av[4], bv[4];
            for (int i = 0; i < 4; ++i) av[i] = *(const f4*)&As[tn + 16 * i][kk * 4];
            for (int j = 0; j < 4; ++j) bv[j] = *(const f4*)&Bs[te + 16 * j][kk * 4];
            for (int i = 0; i < 4; ++i)
                for (int j = 0; j < 4; ++j) acc[i][j] += av[i] * bv[j];
        }
    }
    for (int i = 0; i < 4; ++i)
        for (int j = 0; j < 4; ++j) {
            f4 a = acc[i][j];
            Tt[te + 16 * j][tn + 16 * i] = (bf16)((a.x + a.y) + (a.z + a.w));
        }
    __syncthreads();
    const int b = n0 >> 12, ml = n0 & 4095;
    for (int i2 = 0; i2 < 2; ++i2) {
        int id = i2 * 256 + t, er = id >> 3, g = (id & 7) * 8;
        *(bf16x8*)&VT[((size_t)b * 512 + e0 + er) * 4096 + ml + g] =
            *(bf16x8*)&Tt[er][g];
    }
}

// ---------------------------------------------------------------------------
// K2: wave-per-row fp64 normalize -> fp32 qn + fp16 qh.
// ---------------------------------------------------------------------------
__global__ __launch_bounds__(256) void norm_q(const double* __restrict__ Q,
                                              float* __restrict__ QF,
                                              f16* __restrict__ QH) {
    const int wave = threadIdx.x >> 6, lane = threadIdx.x & 63;
    const int row = blockIdx.x * 4 + wave;
    const double* q = Q + (size_t)row * 512;
    double x[8];
    double s = 0.0;
    for (int j = 0; j < 8; ++j) { x[j] = q[lane * 8 + j]; s += x[j] * x[j]; }
    for (int off = 1; off < 64; off <<= 1) s += __shfl_xor(s, off);
    double nm = fmax(sqrt(s), 1e-12);
    for (int j = 0; j < 8; ++j) {
        float qf = (float)(x[j] / nm);
        QF[(size_t)row * 512 + lane * 8 + j] = qf;
        QH[(size_t)row * 512 + lane * 8 + j] = (f16)qf;
    }
}

// ---------------------------------------------------------------------------
// K3 (R11): 1-term fp16 MFMA cosine + narrow-band fp32 verify.
// grid 256, 512 thr. bid&7 -> (batch, m-half) pinned per XCD; bid>>3 -> n0.
// 8 waves = 4 row-groups (32 rows) x 2 m-groups (64 m). A in regs (full K),
// B fp16 double-buffered LDS with XOR slot swizzle, early-issued loads.
// ---------------------------------------------------------------------------
__global__ __launch_bounds__(512) void qk_mfma(const float* __restrict__ QF,
                                               const f16* __restrict__ QHB,
                                               uint16_t* __restrict__ counts,
                                               uint16_t* __restrict__ idxs,
                                               bf16* __restrict__ vals) {
    __shared__ f16 Bs[2][128][128];       // 64 KB, slot-swizzled
    __shared__ int cnt[128];
    __shared__ int bcnt;
    __shared__ uint32_t blist[BCAPC];     // 2 KB

    const int t = threadIdx.x;
    const int wave = t >> 6, lane = t & 63;
    const int ln16 = lane & 15, hi4 = lane >> 4;
    const int rg = wave >> 1, mg = wave & 1;
    const int grp = blockIdx.x & 7;            // one (batch,half) per XCD
    const int b = grp >> 1, half = grp & 1;
    const int n0 = (blockIdx.x >> 3) * 128;
    const size_t nb = (size_t)b * 4096;
    const float* qf = QF + nb * 512;
    const f16* qh = QHB + nb * 512;
    const int mbase = half * 2048;

    // A regs: rows n0 + rg*32 + rt*16 + ln16; slice s -> cols s*32 + hi4*8
    f16x8 A[2][16];
#pragma unroll
    for (int rt = 0; rt < 2; ++rt) {
        const size_t arow = (size_t)(n0 + rg * 32 + rt * 16 + ln16) * 512;
#pragma unroll
        for (int s = 0; s < 16; ++s)
            A[rt][s] = *(const f16x8*)&qh[arow + s * 32 + hi4 * 8];
    }

    if (t < 128) cnt[t] = 0;
    if (t == 0) bcnt = 0;

    // prologue: stage (chunk 0, k0 0) into buf 0 (swizzled slots)
#pragma unroll
    for (int i = 0; i < 4; ++i) {
        int id = i * 512 + t, r = id >> 4, s = id & 15;
        *(f16x8*)&Bs[0][r][(s ^ (r & 15)) * 8] =
            *(const f16x8*)&qh[(size_t)(mbase + r) * 512 + s * 8];
    }
    __syncthreads();

    for (int ch = 0; ch < 16; ++ch) {
        const int mst = mbase + ch * 128;
        f4 S[2][4] = {};
#pragma unroll
        for (int k0i = 0; k0i < 4; ++k0i) {
            const int buf = k0i & 1;
            const bool last = (k0i == 3) && (ch == 15);
            const int nmst = (k0i < 3) ? mst : mst + 128;
            const int nk0 = (k0i < 3) ? (k0i + 1) * 128 : 0;
            f16x8 L[4];
            if (!last) {                        // issue next-step loads EARLY
#pragma unroll
                for (int i = 0; i < 4; ++i) {
                    int id = i * 512 + t, r = id >> 4, s = id & 15;
                    L[i] = *(const f16x8*)&qh[(size_t)(nmst + r) * 512 + nk0 + s * 8];
                }
            }
#pragma unroll
            for (int kk = 0; kk < 4; ++kk) {
                const int s = k0i * 4 + kk;
                const f16x8 a0 = A[0][s], a1 = A[1][s];
#pragma unroll
                for (int tt = 0; tt < 4; ++tt) {
                    const int br = mg * 64 + tt * 16 + ln16;
                    f16x8 bb = *(const f16x8*)&Bs[buf][br][((kk * 4 + hi4) ^ ln16) * 8];
                    S[0][tt] = __builtin_amdgcn_mfma_f32_16x16x32_f16(a0, bb, S[0][tt], 0, 0, 0);
                    S[1][tt] = __builtin_amdgcn_mfma_f32_16x16x32_f16(a1, bb, S[1][tt], 0, 0, 0);
                }
            }
            if (k0i == 3) {                     // chunk complete: threshold
#pragma unroll
                for (int rt = 0; rt < 2; ++rt)
#pragma unroll
                    for (int tt = 0; tt < 4; ++tt) {
                        const int m = mst + mg * 64 + tt * 16 + ln16;
#pragma unroll
                        for (int i = 0; i < 4; ++i) {
                            float cs = S[rt][tt][i];
                            int row = rg * 32 + rt * 16 + hi4 * 4 + i;
                            if (cs > 0.1f + QBAND) {
                                int pos = atomicAdd(&cnt[row], 1);
                                if (pos < CAP2) {
                                    size_t o = ((size_t)(nb + n0 + row) * 2 + half) * CAP2 + pos;
                                    idxs[o] = (uint16_t)m;
                                    vals[o] = (bf16)cs;
                                }
                            } else if (cs > 0.1f - QBAND) {
                                int bp = atomicAdd(&bcnt, 1);
                                if (bp < BCAPC)
                                    blist[bp] = ((uint32_t)row << 12) | (uint32_t)m;
                            }
                        }
                    }
            }
            __syncthreads();           // Bs[buf^1] reads done; blist complete
            if (!last) {
#pragma unroll
                for (int i = 0; i < 4; ++i) {
                    int id = i * 512 + t, r = id >> 4, s = id & 15;
                    *(f16x8*)&Bs[buf ^ 1][r][(s ^ (r & 15)) * 8] = L[i];
                }
            }
            if (k0i == 3) {            // wave-parallel fp32/f64-acc verify
                int nbd = bcnt; if (nbd > BCAPC) nbd = BCAPC;
                for (int p = wave; p < nbd; p += 8) {
                    uint32_t pk = blist[p];
                    int row = (int)(pk >> 12), m = (int)(pk & 4095);
                    const float* qa = qf + (size_t)(n0 + row) * 512;
                    const float* qc = qf + (size_t)m * 512;
                    f4 a0 = *(const f4*)&qa[lane * 8];
                    f4 a1 = *(const f4*)&qa[lane * 8 + 4];
                    f4 c0 = *(const f4*)&qc[lane * 8];
                    f4 c1 = *(const f4*)&qc[lane * 8 + 4];
                    double s = (double)a0.x * c0.x + (double)a0.y * c0.y +
                               (double)a0.z * c0.z + (double)a0.w * c0.w +
                               (double)a1.x * c1.x + (double)a1.y * c1.y +
                               (double)a1.z * c1.z + (double)a1.w * c1.w;
                    for (int off = 1; off < 64; off <<= 1) s += __shfl_xor(s, off);
                    if (lane == 0 && s > 0.1) {
                        int pos = atomicAdd(&cnt[row], 1);
                        if (pos < CAP2) {
                            size_t o = ((size_t)(nb + n0 + row) * 2 + half) * CAP2 + pos;
                            idxs[o] = (uint16_t)m;
                            vals[o] = (bf16)(float)s;
                        }
                    }
                }
            }
            __syncthreads();           // staging writes visible; verify done
            if (k0i == 3 && t == 0) bcnt = 0;
        }
    }
    __syncthreads();
    if (t < 128) {
        int c = cnt[t];
        counts[(size_t)(nb + n0 + t) * 2 + half] = (uint16_t)(c > CAP2 ? CAP2 : c);
    }
}

// ---------------------------------------------------------------------------
// K4 (R10, proven): 32x32x16-MFMA PV + fused LayerNorm. grid 256, 512 thr.
// ---------------------------------------------------------------------------
__global__ __launch_bounds__(512, 2) void pv_mfma(const bf16* __restrict__ VT,
                                                  const uint16_t* __restrict__ counts,
                                                  const uint16_t* __restrict__ idxs,
                                                  const bf16* __restrict__ vals,
                                                  const float* __restrict__ gamma,
                                                  const float* __restrict__ beta,
                                                  float* __restrict__ Out) {
    __shared__ __align__(16) char smemraw[147456];   // Vts 128K + Wsm 16K
    bf16 (*Vts)[128] = (bf16(*)[128])smemraw;        // [512 e][128 m] swz
    bf16 (*Wsm)[128] = (bf16(*)[128])(smemraw + 131072); // [64 n][128 m] swz

    const int t = threadIdx.x;
    const int wave = t >> 6, lane = t & 63;
    const int l31 = lane & 31, l15 = lane & 15, g = lane >> 5;
    const int grp = blockIdx.x & 7;                  // XCD-pinned batch panel
    const int b = grp >> 1;
    const int n0 = ((blockIdx.x >> 3) + ((grp & 1) ? 32 : 0)) * 64;
    const size_t nb = (size_t)b * 4096;
    const bf16* vtb = VT + (size_t)b * 512 * 4096;

    // owner (t<64) list state
    int myc0 = 0, myc1 = 0, cu = 0, pb = 0;
    u16x8 pi0 = {}, pi1 = {};
    bf16x8 pv0 = {}, pv1 = {};
    size_t base0 = 0, base1 = 0;
    if (t < 64) {
        myc0 = (int)counts[(size_t)(nb + n0 + t) * 2 + 0];
        myc1 = (int)counts[(size_t)(nb + n0 + t) * 2 + 1];
        if (myc0 > CAP2) myc0 = CAP2;
        if (myc1 > CAP2) myc1 = CAP2;
        base0 = ((size_t)(nb + n0 + t) * 2 + 0) * CAP2;
        base1 = ((size_t)(nb + n0 + t) * 2 + 1) * CAP2;
        pi0 = *(const u16x8*)&idxs[base0];
        pi1 = *(const u16x8*)&idxs[base0 + 8];
        pv0 = *(const bf16x8*)&vals[base0];
        pv1 = *(const bf16x8*)&vals[base0 + 8];
    }

    // prologue: stage chunk 0 into regs
    bf16x8 L[16];
#pragma unroll
    for (int i = 0; i < 16; ++i) {
        int id = i * 512 + t, r = id >> 4, s = id & 15;
        L[i] = *(const bf16x8*)&vtb[(size_t)r * 4096 + s * 8];
    }

    f16v acc[2][2] = {};   // [nt][et]: rows nt*32+cdrow, cols wave*64+et*32+l31

    for (int ch = 0; ch < 32; ++ch) {
        __syncthreads();               // (a) prev MFMA done reading Vts/Wsm
#pragma unroll
        for (int i = 0; i < 16; ++i) {
            int id = i * 512 + t, r = id >> 4, s = id & 15;
            *(bf16x8*)&Vts[r][(s ^ (r & 15)) << 3] = L[i];
        }
        if (t < 64) {
            bf16 z0 = (bf16)0.0f;
            bf16x8 zv = {z0, z0, z0, z0, z0, z0, z0, z0};
#pragma unroll
            for (int sj = 0; sj < 16; ++sj) *(bf16x8*)&Wsm[t][sj * 8] = zv;
            if (ch == 16) cu = 0;
            const int m0l = ch * 128;
            const int myc = (ch >= 16) ? myc1 : myc0;
            const size_t base = (ch >= 16) ? base1 : base0;
            int end = cu;
#pragma unroll
            for (int j = 0; j < 16; ++j) {
                int pos = pb + j;
                int mi = (j < 8) ? (int)pi0[j] : (int)pi1[j - 8];
                bf16 vv = (j < 8) ? pv0[j] : pv1[j - 8];
                if (pos == end && pos < myc && mi < m0l + 128) {
                    int lo = mi - m0l;
                    Wsm[t][(((lo >> 3) ^ (t & 15)) << 3) | (lo & 7)] = vv;
                    end = pos + 1;
                }
            }
            if (end == pb + 16) {      // rare spill past prefetch window
                while (end < myc) {
                    int mi = (int)idxs[base + end];
                    if (mi >= m0l + 128) break;
                    int lo = mi - m0l;
                    Wsm[t][(((lo >> 3) ^ (t & 15)) << 3) | (lo & 7)] =
                        vals[base + end];
                    ++end;
                }
            }
            cu = end;
        }
        __syncthreads();               // (b) Vts/Wsm ready
        if (ch < 31) {
            const int mo = (ch + 1) * 128;
#pragma unroll
            for (int i = 0; i < 16; ++i) {
                int id = i * 512 + t, r = id >> 4, s = id & 15;
                L[i] = *(const bf16x8*)&vtb[(size_t)r * 4096 + mo + s * 8];
            }
            if (t < 64) {
                int ncu = (ch + 1 == 16) ? 0 : cu;
                const size_t nbase = (ch + 1 >= 16) ? base1 : base0;
                pb = ncu & ~7;
                pi0 = *(const u16x8*)&idxs[nbase + pb];
                pi1 = *(const u16x8*)&idxs[nbase + pb + 8];
                pv0 = *(const bf16x8*)&vals[nbase + pb];
                pv1 = *(const bf16x8*)&vals[nbase + pb + 8];
            }
        }
#pragma unroll
        for (int ks = 0; ks < 8; ++ks) {
            const int sw = (((ks * 2 + g) ^ l15) << 3);
            bf16x8 A0 = *(const bf16x8*)&Wsm[l31][sw];
            bf16x8 A1 = *(const bf16x8*)&Wsm[32 + l31][sw];
            bf16x8 B0 = *(const bf16x8*)&Vts[wave * 64 + l31][sw];
            bf16x8 B1 = *(const bf16x8*)&Vts[wave * 64 + 32 + l31][sw];
            acc[0][0] = __builtin_amdgcn_mfma_f32_32x32x16_bf16(A0, B0, acc[0][0], 0, 0, 0);
            acc[0][1] = __builtin_amdgcn_mfma_f32_32x32x16_bf16(A0, B1, acc[0][1], 0, 0, 0);
            acc[1][0] = __builtin_amdgcn_mfma_f32_32x32x16_bf16(A1, B0, acc[1][0], 0, 0, 0);
            acc[1][1] = __builtin_amdgcn_mfma_f32_32x32x16_bf16(A1, B1, acc[1][1], 0, 0, 0);
        }
    }

    // ---- fused LayerNorm over 512 cols (red/mrs alias dead Vts) ----
    __syncthreads();
    float* red = (float*)smemraw;            // [8][64][2]
    float* mrs = (float*)(smemraw + 4096);   // mu[64], rs[64]
#pragma unroll
    for (int nt = 0; nt < 2; ++nt)
#pragma unroll
        for (int r = 0; r < 16; ++r) {
            float v0 = acc[nt][0][r], v1 = acc[nt][1][r];
            float s = v0 + v1, q = v0 * v0 + v1 * v1;
            for (int off = 1; off < 32; off <<= 1) {
                s += __shfl_xor(s, off);
                q += __shfl_xor(q, off);
            }
            if (l31 == 0) {
                int nloc = nt * 32 + (r & 3) + 8 * (r >> 2) + 4 * g;
                red[(wave * 64 + nloc) * 2] = s;
                red[(wave * 64 + nloc) * 2 + 1] = q;
            }
        }
    __syncthreads();
    if (t < 64) {
        float s = 0.f, q = 0.f;
        for (int w2 = 0; w2 < 8; ++w2) {
            s += red[(w2 * 64 + t) * 2];
            q += red[(w2 * 64 + t) * 2 + 1];
        }
        float mu = s * (1.0f / 512.0f);
        float var = q * (1.0f / 512.0f) - mu * mu;
        mrs[t] = mu;
        mrs[64 + t] = rsqrtf(var + 1e-5f);
    }
    __syncthreads();
    const float g0 = gamma[wave * 64 + l31], g1 = gamma[wave * 64 + 32 + l31];
    const float b0 = beta[wave * 64 + l31], b1 = beta[wave * 64 + 32 + l31];
#pragma unroll
    for (int nt = 0; nt < 2; ++nt)
#pragma unroll
        for (int r = 0; r < 16; ++r) {
            int nloc = nt * 32 + (r & 3) + 8 * (r >> 2) + 4 * g;
            float mu = mrs[nloc], rs = mrs[64 + nloc];
            size_t ro = (nb + n0 + nloc) * 512;
            float y0 = (acc[nt][0][r] - mu) * rs * g0 + b0;
            float y1 = (acc[nt][1][r] - mu) * rs * g1 + b1;
            Out[ro + wave * 64 + l31] = y0;
            Out[ro + wave * 64 + 32 + l31] = y1;
        }
}

// ---------------------------------------------------------------------------
extern "C" void kernel_launch(void* const* d_in, const int* in_sizes, int n_in,
                              void* d_out, int out_size, void* d_ws, size_t ws_size,
                              hipStream_t stream) {
    const float* x     = (const float*)d_in[0];
    const float* wqk   = (const float*)d_in[1];
    const float* wv    = (const float*)d_in[2];
    const float* gamma = (const float*)d_in[3];
    const float* beta  = (const float*)d_in[4];
    float* out = (float*)d_out;

    char* ws = (char*)d_ws;
    // fp64 qtmp [0, 67,108,864) dies after norm_q; idxs+vals recycle it EXACTLY.
    uint16_t* idxs   = (uint16_t*)ws;                        // 33,554,432 B
    bf16*     vals   = (bf16*)(ws + 33554432);               // 33,554,432 B -> 67,108,864
    float*    qn32   = (float*)(ws + 67108864);              // 33,554,432 B -> 100,663,296
    f16*      qh16   = (f16*)(ws + 100663296);               // 16,777,216 B -> 117,440,512
    // [117,440,512 .. 134,217,728) dead (was qlo)
    bf16*     vt     = (bf16*)(ws + 134217728);              // 16,777,216 B -> 150,994,944
    uint16_t* counts = (uint16_t*)(ws + 150994944);          //     65,536 B -> 151,060,480
    double*   qtmp   = (double*)ws;                          // TEMP, dies after norm_q
    const size_t need = 151060480;  // == R2-proven ws_size lower bound
    if (ws_size < need) return;

    proj_f64<<<dim3(256, 8), 256, 0, stream>>>(x, wqk, qtmp);
    proj_v<<<dim3(256, 8), 256, 0, stream>>>(x, wv, vt);
    norm_q<<<4096, 256, 0, stream>>>(qtmp, qn32, qh16);
    qk_mfma<<<256, 512, 0, stream>>>(qn32, qh16, counts, idxs, vals);
    pv_mfma<<<256, 512, 0, stream>>>(vt, counts, idxs, vals, gamma, beta, out);
}

// Round 7
// 645.132 us; speedup vs baseline: 1.8941x; 1.1566x over previous
//
#include <hip/hip_runtime.h>
#include <hip/hip_bf16.h>
#include <stdint.h>

// SimTransformer — fp32 I/O. R13: A/B isolation after R12's structural fail
// (absmax 6.28). proj_q64 (f64-MFMA, the only unverified-layout element)
// REVERTED to R11's proven vector-fp64 proj_f64; proj_v16 (fp16 MFMA,
// mapping isomorphic to proven qk_mfma) KEPT. Everything else = R11 (746us).

typedef __bf16 bf16;
typedef __bf16 bf16x8 __attribute__((ext_vector_type(8)));
typedef _Float16 f16;
typedef _Float16 f16x8 __attribute__((ext_vector_type(8)));
typedef unsigned short u16x8 __attribute__((ext_vector_type(8)));
typedef float f4 __attribute__((ext_vector_type(4)));
typedef float f16v __attribute__((ext_vector_type(16)));

#define CAP2 512     // per-row per-m-half list cap (mean ~25/half)
#define QBAND 2e-4f  // borderline band around 0.1 (fp16 1-term sigma ~9e-6)
#define BCAPC 512    // borderline pairs per 128-m chunk (mean ~11)

// ---------------------------------------------------------------------------
// K1 (R11, proven): Q[n,e] = sum_d X[n,d]*W[e,d] in fp64. 64x64 tile, 256 thr.
// ---------------------------------------------------------------------------
__global__ __launch_bounds__(256) void proj_f64(const float* __restrict__ X,
                                                const float* __restrict__ W,
                                                double* __restrict__ Q) {
    __shared__ double As[64][66];
    __shared__ double Bs[64][66];
    const int t = threadIdx.x, tn = t >> 4, te = t & 15;
    const int n0 = blockIdx.x * 64, e0 = blockIdx.y * 64;
    double acc[4][4] = {};
    for (int p = 0; p < 8; ++p) {
        __syncthreads();
        for (int q = 0; q < 16; ++q) {
            int id = q * 256 + t, r = id >> 6, c = id & 63;
            As[r][c] = (double)X[(size_t)(n0 + r) * 512 + p * 64 + c];
            Bs[r][c] = (double)W[(size_t)(e0 + r) * 512 + p * 64 + c];
        }
        __syncthreads();
        for (int kk = 0; kk < 64; ++kk) {
            double av[4], bv[4];
            for (int i = 0; i < 4; ++i) av[i] = As[tn + 16 * i][kk];
            for (int j = 0; j < 4; ++j) bv[j] = Bs[te + 16 * j][kk];
            for (int i = 0; i < 4; ++i)
                for (int j = 0; j < 4; ++j) acc[i][j] += av[i] * bv[j];
        }
    }
    for (int i = 0; i < 4; ++i)
        for (int j = 0; j < 4; ++j)
            Q[(size_t)(n0 + tn + 16 * i) * 512 + e0 + te + 16 * j] = acc[i][j];
}

// ---------------------------------------------------------------------------
// K1b (R12, kept): VT[b][e][m] = (X Wv^T)[m,e] via fp16 MFMA. 64e x 128m
// tile, 256 thr. A = W-rows in regs (16 slices), X staged f16 in XOR-swizzled
// LDS (two 256-wide K phases). D[e][m] writes VT directly.
// ---------------------------------------------------------------------------
__global__ __launch_bounds__(256) void proj_v16(const float* __restrict__ X,
                                                const float* __restrict__ W,
                                                bf16* __restrict__ VT) {
    __shared__ f16 Xs[128][256];   // 64 KB, slot-swizzled
    const int t = threadIdx.x;
    const int wave = t >> 6, lane = t & 63;
    const int lo = lane & 15, h = lane >> 4;
    const int m0g = blockIdx.x * 128;
    const int e0 = blockIdx.y * 64;
    const int b = m0g >> 12, ml = m0g & 4095;

    // A: W rows e0 + 16*wave + lo, 16 k-slices of f16x8
    f16x8 A[16];
    {
        const size_t arow = (size_t)(e0 + wave * 16 + lo) * 512;
#pragma unroll
        for (int s = 0; s < 16; ++s) {
            f4 w0 = *(const f4*)&W[arow + s * 32 + h * 8];
            f4 w1 = *(const f4*)&W[arow + s * 32 + h * 8 + 4];
            f16x8 a;
            a[0] = (f16)w0.x; a[1] = (f16)w0.y; a[2] = (f16)w0.z; a[3] = (f16)w0.w;
            a[4] = (f16)w1.x; a[5] = (f16)w1.y; a[6] = (f16)w1.z; a[7] = (f16)w1.w;
            A[s] = a;
        }
    }

    f4 acc[8] = {};
    for (int ph = 0; ph < 2; ++ph) {
        __syncthreads();
#pragma unroll
        for (int i = 0; i < 16; ++i) {
            int id = i * 256 + t;
            int r = id >> 5, s8 = id & 31;
            f4 x0 = *(const f4*)&X[(size_t)(m0g + r) * 512 + ph * 256 + s8 * 8];
            f4 x1 = *(const f4*)&X[(size_t)(m0g + r) * 512 + ph * 256 + s8 * 8 + 4];
            f16x8 v;
            v[0] = (f16)x0.x; v[1] = (f16)x0.y; v[2] = (f16)x0.z; v[3] = (f16)x0.w;
            v[4] = (f16)x1.x; v[5] = (f16)x1.y; v[6] = (f16)x1.z; v[7] = (f16)x1.w;
            int sl = (s8 & 16) | ((s8 ^ r) & 15);
            *(f16x8*)&Xs[r][sl * 8] = v;
        }
        __syncthreads();
#pragma unroll
        for (int s = 0; s < 8; ++s) {
            const f16x8 a = A[ph * 8 + s];
#pragma unroll
            for (int jt = 0; jt < 8; ++jt) {
                int rr = jt * 16 + lo;
                int c8 = s * 4 + h;
                int sl = (c8 & 16) | ((c8 ^ rr) & 15);
                f16x8 bb = *(const f16x8*)&Xs[rr][sl * 8];
                acc[jt] = __builtin_amdgcn_mfma_f32_16x16x32_f16(a, bb, acc[jt], 0, 0, 0);
            }
        }
    }
#pragma unroll
    for (int jt = 0; jt < 8; ++jt)
#pragma unroll
        for (int r = 0; r < 4; ++r) {
            int e = e0 + wave * 16 + h * 4 + r;
            int m = ml + jt * 16 + lo;
            VT[((size_t)b * 512 + e) * 4096 + m] = (bf16)acc[jt][r];
        }
}

// ---------------------------------------------------------------------------
// K2 (proven): wave-per-row fp64 normalize -> fp32 qn + fp16 qh.
// ---------------------------------------------------------------------------
__global__ __launch_bounds__(256) void norm_q(const double* __restrict__ Q,
                                              float* __restrict__ QF,
                                              f16* __restrict__ QH) {
    const int wave = threadIdx.x >> 6, lane = threadIdx.x & 63;
    const int row = blockIdx.x * 4 + wave;
    const double* q = Q + (size_t)row * 512;
    double x[8];
    double s = 0.0;
    for (int j = 0; j < 8; ++j) { x[j] = q[lane * 8 + j]; s += x[j] * x[j]; }
    for (int off = 1; off < 64; off <<= 1) s += __shfl_xor(s, off);
    double nm = fmax(sqrt(s), 1e-12);
    for (int j = 0; j < 8; ++j) {
        float qf = (float)(x[j] / nm);
        QF[(size_t)row * 512 + lane * 8 + j] = qf;
        QH[(size_t)row * 512 + lane * 8 + j] = (f16)qf;
    }
}

// ---------------------------------------------------------------------------
// K3 (R11, proven): 1-term fp16 MFMA cosine + narrow-band fp32 verify.
// ---------------------------------------------------------------------------
__global__ __launch_bounds__(512) void qk_mfma(const float* __restrict__ QF,
                                               const f16* __restrict__ QHB,
                                               uint16_t* __restrict__ counts,
                                               uint16_t* __restrict__ idxs,
                                               bf16* __restrict__ vals) {
    __shared__ f16 Bs[2][128][128];       // 64 KB, slot-swizzled
    __shared__ int cnt[128];
    __shared__ int bcnt;
    __shared__ uint32_t blist[BCAPC];     // 2 KB

    const int t = threadIdx.x;
    const int wave = t >> 6, lane = t & 63;
    const int ln16 = lane & 15, hi4 = lane >> 4;
    const int rg = wave >> 1, mg = wave & 1;
    const int grp = blockIdx.x & 7;            // one (batch,half) per XCD
    const int b = grp >> 1, half = grp & 1;
    const int n0 = (blockIdx.x >> 3) * 128;
    const size_t nb = (size_t)b * 4096;
    const float* qf = QF + nb * 512;
    const f16* qh = QHB + nb * 512;
    const int mbase = half * 2048;

    f16x8 A[2][16];
#pragma unroll
    for (int rt = 0; rt < 2; ++rt) {
        const size_t arow = (size_t)(n0 + rg * 32 + rt * 16 + ln16) * 512;
#pragma unroll
        for (int s = 0; s < 16; ++s)
            A[rt][s] = *(const f16x8*)&qh[arow + s * 32 + hi4 * 8];
    }

    if (t < 128) cnt[t] = 0;
    if (t == 0) bcnt = 0;

#pragma unroll
    for (int i = 0; i < 4; ++i) {
        int id = i * 512 + t, r = id >> 4, s = id & 15;
        *(f16x8*)&Bs[0][r][(s ^ (r & 15)) * 8] =
            *(const f16x8*)&qh[(size_t)(mbase + r) * 512 + s * 8];
    }
    __syncthreads();

    for (int ch = 0; ch < 16; ++ch) {
        const int mst = mbase + ch * 128;
        f4 S[2][4] = {};
#pragma unroll
        for (int k0i = 0; k0i < 4; ++k0i) {
            const int buf = k0i & 1;
            const bool last = (k0i == 3) && (ch == 15);
            const int nmst = (k0i < 3) ? mst : mst + 128;
            const int nk0 = (k0i < 3) ? (k0i + 1) * 128 : 0;
            f16x8 L[4];
            if (!last) {                        // issue next-step loads EARLY
#pragma unroll
                for (int i = 0; i < 4; ++i) {
                    int id = i * 512 + t, r = id >> 4, s = id & 15;
                    L[i] = *(const f16x8*)&qh[(size_t)(nmst + r) * 512 + nk0 + s * 8];
                }
            }
#pragma unroll
            for (int kk = 0; kk < 4; ++kk) {
                const int s = k0i * 4 + kk;
                const f16x8 a0 = A[0][s], a1 = A[1][s];
#pragma unroll
                for (int tt = 0; tt < 4; ++tt) {
                    const int br = mg * 64 + tt * 16 + ln16;
                    f16x8 bb = *(const f16x8*)&Bs[buf][br][((kk * 4 + hi4) ^ ln16) * 8];
                    S[0][tt] = __builtin_amdgcn_mfma_f32_16x16x32_f16(a0, bb, S[0][tt], 0, 0, 0);
                    S[1][tt] = __builtin_amdgcn_mfma_f32_16x16x32_f16(a1, bb, S[1][tt], 0, 0, 0);
                }
            }
            if (k0i == 3) {                     // chunk complete: threshold
#pragma unroll
                for (int rt = 0; rt < 2; ++rt)
#pragma unroll
                    for (int tt = 0; tt < 4; ++tt) {
                        const int m = mst + mg * 64 + tt * 16 + ln16;
#pragma unroll
                        for (int i = 0; i < 4; ++i) {
                            float cs = S[rt][tt][i];
                            int row = rg * 32 + rt * 16 + hi4 * 4 + i;
                            if (cs > 0.1f + QBAND) {
                                int pos = atomicAdd(&cnt[row], 1);
                                if (pos < CAP2) {
                                    size_t o = ((size_t)(nb + n0 + row) * 2 + half) * CAP2 + pos;
                                    idxs[o] = (uint16_t)m;
                                    vals[o] = (bf16)cs;
                                }
                            } else if (cs > 0.1f - QBAND) {
                                int bp = atomicAdd(&bcnt, 1);
                                if (bp < BCAPC)
                                    blist[bp] = ((uint32_t)row << 12) | (uint32_t)m;
                            }
                        }
                    }
            }
            __syncthreads();           // Bs[buf^1] reads done; blist complete
            if (!last) {
#pragma unroll
                for (int i = 0; i < 4; ++i) {
                    int id = i * 512 + t, r = id >> 4, s = id & 15;
                    *(f16x8*)&Bs[buf ^ 1][r][(s ^ (r & 15)) * 8] = L[i];
                }
            }
            if (k0i == 3) {            // wave-parallel fp32/f64-acc verify
                int nbd = bcnt; if (nbd > BCAPC) nbd = BCAPC;
                for (int p = wave; p < nbd; p += 8) {
                    uint32_t pk = blist[p];
                    int row = (int)(pk >> 12), m = (int)(pk & 4095);
                    const float* qa = qf + (size_t)(n0 + row) * 512;
                    const float* qc = qf + (size_t)m * 512;
                    f4 a0 = *(const f4*)&qa[lane * 8];
                    f4 a1 = *(const f4*)&qa[lane * 8 + 4];
                    f4 c0 = *(const f4*)&qc[lane * 8];
                    f4 c1 = *(const f4*)&qc[lane * 8 + 4];
                    double s = (double)a0.x * c0.x + (double)a0.y * c0.y +
                               (double)a0.z * c0.z + (double)a0.w * c0.w +
                               (double)a1.x * c1.x + (double)a1.y * c1.y +
                               (double)a1.z * c1.z + (double)a1.w * c1.w;
                    for (int off = 1; off < 64; off <<= 1) s += __shfl_xor(s, off);
                    if (lane == 0 && s > 0.1) {
                        int pos = atomicAdd(&cnt[row], 1);
                        if (pos < CAP2) {
                            size_t o = ((size_t)(nb + n0 + row) * 2 + half) * CAP2 + pos;
                            idxs[o] = (uint16_t)m;
                            vals[o] = (bf16)(float)s;
                        }
                    }
                }
            }
            __syncthreads();           // staging writes visible; verify done
            if (k0i == 3 && t == 0) bcnt = 0;
        }
    }
    __syncthreads();
    if (t < 128) {
        int c = cnt[t];
        counts[(size_t)(nb + n0 + t) * 2 + half] = (uint16_t)(c > CAP2 ? CAP2 : c);
    }
}

// ---------------------------------------------------------------------------
// K4 (R10, proven): 32x32x16-MFMA PV + fused LayerNorm. grid 256, 512 thr.
// ---------------------------------------------------------------------------
__global__ __launch_bounds__(512, 2) void pv_mfma(const bf16* __restrict__ VT,
                                                  const uint16_t* __restrict__ counts,
                                                  const uint16_t* __restrict__ idxs,
                                                  const bf16* __restrict__ vals,
                                                  const float* __restrict__ gamma,
                                                  const float* __restrict__ beta,
                                                  float* __restrict__ Out) {
    __shared__ __align__(16) char smemraw[147456];   // Vts 128K + Wsm 16K
    bf16 (*Vts)[128] = (bf16(*)[128])smemraw;        // [512 e][128 m] swz
    bf16 (*Wsm)[128] = (bf16(*)[128])(smemraw + 131072); // [64 n][128 m] swz

    const int t = threadIdx.x;
    const int wave = t >> 6, lane = t & 63;
    const int l31 = lane & 31, l15 = lane & 15, g = lane >> 5;
    const int grp = blockIdx.x & 7;                  // XCD-pinned batch panel
    const int b = grp >> 1;
    const int n0 = ((blockIdx.x >> 3) + ((grp & 1) ? 32 : 0)) * 64;
    const size_t nb = (size_t)b * 4096;
    const bf16* vtb = VT + (size_t)b * 512 * 4096;

    int myc0 = 0, myc1 = 0, cu = 0, pb = 0;
    u16x8 pi0 = {}, pi1 = {};
    bf16x8 pv0 = {}, pv1 = {};
    size_t base0 = 0, base1 = 0;
    if (t < 64) {
        myc0 = (int)counts[(size_t)(nb + n0 + t) * 2 + 0];
        myc1 = (int)counts[(size_t)(nb + n0 + t) * 2 + 1];
        if (myc0 > CAP2) myc0 = CAP2;
        if (myc1 > CAP2) myc1 = CAP2;
        base0 = ((size_t)(nb + n0 + t) * 2 + 0) * CAP2;
        base1 = ((size_t)(nb + n0 + t) * 2 + 1) * CAP2;
        pi0 = *(const u16x8*)&idxs[base0];
        pi1 = *(const u16x8*)&idxs[base0 + 8];
        pv0 = *(const bf16x8*)&vals[base0];
        pv1 = *(const bf16x8*)&vals[base0 + 8];
    }

    bf16x8 L[16];
#pragma unroll
    for (int i = 0; i < 16; ++i) {
        int id = i * 512 + t, r = id >> 4, s = id & 15;
        L[i] = *(const bf16x8*)&vtb[(size_t)r * 4096 + s * 8];
    }

    f16v acc[2][2] = {};   // [nt][et]

    for (int ch = 0; ch < 32; ++ch) {
        __syncthreads();
#pragma unroll
        for (int i = 0; i < 16; ++i) {
            int id = i * 512 + t, r = id >> 4, s = id & 15;
            *(bf16x8*)&Vts[r][(s ^ (r & 15)) << 3] = L[i];
        }
        if (t < 64) {
            bf16 z0 = (bf16)0.0f;
            bf16x8 zv = {z0, z0, z0, z0, z0, z0, z0, z0};
#pragma unroll
            for (int sj = 0; sj < 16; ++sj) *(bf16x8*)&Wsm[t][sj * 8] = zv;
            if (ch == 16) cu = 0;
            const int m0l = ch * 128;
            const int myc = (ch >= 16) ? myc1 : myc0;
            const size_t base = (ch >= 16) ? base1 : base0;
            int end = cu;
#pragma unroll
            for (int j = 0; j < 16; ++j) {
                int pos = pb + j;
                int mi = (j < 8) ? (int)pi0[j] : (int)pi1[j - 8];
                bf16 vv = (j < 8) ? pv0[j] : pv1[j - 8];
                if (pos == end && pos < myc && mi < m0l + 128) {
                    int lo = mi - m0l;
                    Wsm[t][(((lo >> 3) ^ (t & 15)) << 3) | (lo & 7)] = vv;
                    end = pos + 1;
                }
            }
            if (end == pb + 16) {
                while (end < myc) {
                    int mi = (int)idxs[base + end];
                    if (mi >= m0l + 128) break;
                    int lo = mi - m0l;
                    Wsm[t][(((lo >> 3) ^ (t & 15)) << 3) | (lo & 7)] =
                        vals[base + end];
                    ++end;
                }
            }
            cu = end;
        }
        __syncthreads();
        if (ch < 31) {
            const int mo = (ch + 1) * 128;
#pragma unroll
            for (int i = 0; i < 16; ++i) {
                int id = i * 512 + t, r = id >> 4, s = id & 15;
                L[i] = *(const bf16x8*)&vtb[(size_t)r * 4096 + mo + s * 8];
            }
            if (t < 64) {
                int ncu = (ch + 1 == 16) ? 0 : cu;
                const size_t nbase = (ch + 1 >= 16) ? base1 : base0;
                pb = ncu & ~7;
                pi0 = *(const u16x8*)&idxs[nbase + pb];
                pi1 = *(const u16x8*)&idxs[nbase + pb + 8];
                pv0 = *(const bf16x8*)&vals[nbase + pb];
                pv1 = *(const bf16x8*)&vals[nbase + pb + 8];
            }
        }
#pragma unroll
        for (int ks = 0; ks < 8; ++ks) {
            const int sw = (((ks * 2 + g) ^ l15) << 3);
            bf16x8 A0 = *(const bf16x8*)&Wsm[l31][sw];
            bf16x8 A1 = *(const bf16x8*)&Wsm[32 + l31][sw];
            bf16x8 B0 = *(const bf16x8*)&Vts[wave * 64 + l31][sw];
            bf16x8 B1 = *(const bf16x8*)&Vts[wave * 64 + 32 + l31][sw];
            acc[0][0] = __builtin_amdgcn_mfma_f32_32x32x16_bf16(A0, B0, acc[0][0], 0, 0, 0);
            acc[0][1] = __builtin_amdgcn_mfma_f32_32x32x16_bf16(A0, B1, acc[0][1], 0, 0, 0);
            acc[1][0] = __builtin_amdgcn_mfma_f32_32x32x16_bf16(A1, B0, acc[1][0], 0, 0, 0);
            acc[1][1] = __builtin_amdgcn_mfma_f32_32x32x16_bf16(A1, B1, acc[1][1], 0, 0, 0);
        }
    }

    // ---- fused LayerNorm over 512 cols ----
    __syncthreads();
    float* red = (float*)smemraw;            // [8][64][2]
    float* mrs = (float*)(smemraw + 4096);   // mu[64], rs[64]
#pragma unroll
    for (int nt = 0; nt < 2; ++nt)
#pragma unroll
        for (int r = 0; r < 16; ++r) {
            float v0 = acc[nt][0][r], v1 = acc[nt][1][r];
            float s = v0 + v1, q = v0 * v0 + v1 * v1;
            for (int off = 1; off < 32; off <<= 1) {
                s += __shfl_xor(s, off);
                q += __shfl_xor(q, off);
            }
            if (l31 == 0) {
                int nloc = nt * 32 + (r & 3) + 8 * (r >> 2) + 4 * g;
                red[(wave * 64 + nloc) * 2] = s;
                red[(wave * 64 + nloc) * 2 + 1] = q;
            }
        }
    __syncthreads();
    if (t < 64) {
        float s = 0.f, q = 0.f;
        for (int w2 = 0; w2 < 8; ++w2) {
            s += red[(w2 * 64 + t) * 2];
            q += red[(w2 * 64 + t) * 2 + 1];
        }
        float mu = s * (1.0f / 512.0f);
        float var = q * (1.0f / 512.0f) - mu * mu;
        mrs[t] = mu;
        mrs[64 + t] = rsqrtf(var + 1e-5f);
    }
    __syncthreads();
    const float g0 = gamma[wave * 64 + l31], g1 = gamma[wave * 64 + 32 + l31];
    const float b0 = beta[wave * 64 + l31], b1 = beta[wave * 64 + 32 + l31];
#pragma unroll
    for (int nt = 0; nt < 2; ++nt)
#pragma unroll
        for (int r = 0; r < 16; ++r) {
            int nloc = nt * 32 + (r & 3) + 8 * (r >> 2) + 4 * g;
            float mu = mrs[nloc], rs = mrs[64 + nloc];
            size_t ro = (nb + n0 + nloc) * 512;
            float y0 = (acc[nt][0][r] - mu) * rs * g0 + b0;
            float y1 = (acc[nt][1][r] - mu) * rs * g1 + b1;
            Out[ro + wave * 64 + l31] = y0;
            Out[ro + wave * 64 + 32 + l31] = y1;
        }
}

// ---------------------------------------------------------------------------
extern "C" void kernel_launch(void* const* d_in, const int* in_sizes, int n_in,
                              void* d_out, int out_size, void* d_ws, size_t ws_size,
                              hipStream_t stream) {
    const float* x     = (const float*)d_in[0];
    const float* wqk   = (const float*)d_in[1];
    const float* wv    = (const float*)d_in[2];
    const float* gamma = (const float*)d_in[3];
    const float* beta  = (const float*)d_in[4];
    float* out = (float*)d_out;

    char* ws = (char*)d_ws;
    // fp64 qtmp [0, 67,108,864) dies after norm_q; idxs+vals recycle it EXACTLY.
    uint16_t* idxs   = (uint16_t*)ws;                        // 33,554,432 B
    bf16*     vals   = (bf16*)(ws + 33554432);               // -> 67,108,864
    float*    qn32   = (float*)(ws + 67108864);              // -> 100,663,296
    f16*      qh16   = (f16*)(ws + 100663296);               // -> 117,440,512
    // [117,440,512 .. 134,217,728) dead
    bf16*     vt     = (bf16*)(ws + 134217728);              // -> 150,994,944
    uint16_t* counts = (uint16_t*)(ws + 150994944);          // -> 151,060,480
    double*   qtmp   = (double*)ws;                          // TEMP, dies after norm_q
    const size_t need = 151060480;  // == R2-proven ws_size lower bound
    if (ws_size < need) return;

    proj_f64<<<dim3(256, 8), 256, 0, stream>>>(x, wqk, qtmp);
    proj_v16<<<dim3(128, 8), 256, 0, stream>>>(x, wv, vt);
    norm_q<<<4096, 256, 0, stream>>>(qtmp, qn32, qh16);
    qk_mfma<<<256, 512, 0, stream>>>(qn32, qh16, counts, idxs, vals);
    pv_mfma<<<256, 512, 0, stream>>>(vt, counts, idxs, vals, gamma, beta, out);
}

// Round 8
// 630.676 us; speedup vs baseline: 1.9375x; 1.0229x over previous
//
#include <hip/hip_runtime.h>
#include <hip/hip_bf16.h>
#include <stdint.h>

// SimTransformer — fp32 I/O. R14: proj_f64 rebuilt as 128x128-tile, 8x8-per-
// thread fp64 (R13's 4x4 was LDS-duty-bound at 46% of the fp64-FMA pipe).
// double2-chunked XOR-swizzled LDS ([k][ip][tn^k]) -> av broadcast, bv 2-way,
// staging 2-way; ascending-k accumulation preserved -> bit-identical Q ->
// identical decisions -> absmax stays 0.03125.
// proj_v16 / norm_q / qk_mfma / pv_mfma byte-identical to R13 (proven 645us).

typedef __bf16 bf16;
typedef __bf16 bf16x8 __attribute__((ext_vector_type(8)));
typedef _Float16 f16;
typedef _Float16 f16x8 __attribute__((ext_vector_type(8)));
typedef unsigned short u16x8 __attribute__((ext_vector_type(8)));
typedef float f4 __attribute__((ext_vector_type(4)));
typedef float f16v __attribute__((ext_vector_type(16)));
typedef double d2 __attribute__((ext_vector_type(2)));

#define CAP2 512     // per-row per-m-half list cap (mean ~25/half)
#define QBAND 2e-4f  // borderline band around 0.1 (fp16 1-term sigma ~9e-6)
#define BCAPC 512    // borderline pairs per 128-m chunk (mean ~11)

// ---------------------------------------------------------------------------
// K1 (R14): Q[n,e] = sum_d X[n,d]*W[e,d] in fp64. 128x128 tile, 256 thr,
// 8x8 acc per thread. LDS: d2-chunked [k][ip][tn^k] (16 KB each, swizzled).
// ---------------------------------------------------------------------------
__global__ __launch_bounds__(256, 2) void proj_f64(const float* __restrict__ X,
                                                   const float* __restrict__ W,
                                                   double* __restrict__ Q) {
    __shared__ d2 As3[16][4][16];   // [k][ip][tn^k] -> rows (8tn+2ip, +1), col k
    __shared__ d2 Bs3[16][4][16];
    const int t = threadIdx.x;
    const int tn = t >> 4, te = t & 15;
    const int n0 = blockIdx.x * 128, e0 = blockIdx.y * 128;
    double acc[8][8] = {};
    for (int p = 0; p < 32; ++p) {
        __syncthreads();
#pragma unroll
        for (int i = 0; i < 4; ++i) {
            int id = i * 256 + t;               // 1024 ids = 16k x 16tn x 4ip
            int k = id & 15, rtn = (id >> 4) & 15, rip = id >> 8;
            int r0 = rtn * 8 + rip * 2;
            d2 xa, wa;
            xa.x = (double)X[(size_t)(n0 + r0) * 512 + p * 16 + k];
            xa.y = (double)X[(size_t)(n0 + r0 + 1) * 512 + p * 16 + k];
            wa.x = (double)W[(size_t)(e0 + r0) * 512 + p * 16 + k];
            wa.y = (double)W[(size_t)(e0 + r0 + 1) * 512 + p * 16 + k];
            As3[k][rip][rtn ^ k] = xa;
            Bs3[k][rip][rtn ^ k] = wa;
        }
        __syncthreads();
#pragma unroll
        for (int kk = 0; kk < 16; ++kk) {
            double av[8], bv[8];
#pragma unroll
            for (int ip = 0; ip < 4; ++ip) {
                d2 aa = As3[kk][ip][tn ^ kk];
                d2 bb = Bs3[kk][ip][te ^ kk];
                av[ip * 2] = aa.x; av[ip * 2 + 1] = aa.y;
                bv[ip * 2] = bb.x; bv[ip * 2 + 1] = bb.y;
            }
#pragma unroll
            for (int i = 0; i < 8; ++i)
#pragma unroll
                for (int j = 0; j < 8; ++j) acc[i][j] += av[i] * bv[j];
        }
    }
#pragma unroll
    for (int i = 0; i < 8; ++i)
#pragma unroll
        for (int j2 = 0; j2 < 4; ++j2) {
            d2 o; o.x = acc[i][j2 * 2]; o.y = acc[i][j2 * 2 + 1];
            *(d2*)&Q[(size_t)(n0 + tn * 8 + i) * 512 + e0 + te * 8 + j2 * 2] = o;
        }
}

// ---------------------------------------------------------------------------
// K1b (proven R13): VT[b][e][m] = (X Wv^T)[m,e] via fp16 MFMA. 64e x 128m
// tile, 256 thr. A = W-rows in regs, X staged f16 in XOR-swizzled LDS.
// ---------------------------------------------------------------------------
__global__ __launch_bounds__(256) void proj_v16(const float* __restrict__ X,
                                                const float* __restrict__ W,
                                                bf16* __restrict__ VT) {
    __shared__ f16 Xs[128][256];   // 64 KB, slot-swizzled
    const int t = threadIdx.x;
    const int wave = t >> 6, lane = t & 63;
    const int lo = lane & 15, h = lane >> 4;
    const int m0g = blockIdx.x * 128;
    const int e0 = blockIdx.y * 64;
    const int b = m0g >> 12, ml = m0g & 4095;

    f16x8 A[16];
    {
        const size_t arow = (size_t)(e0 + wave * 16 + lo) * 512;
#pragma unroll
        for (int s = 0; s < 16; ++s) {
            f4 w0 = *(const f4*)&W[arow + s * 32 + h * 8];
            f4 w1 = *(const f4*)&W[arow + s * 32 + h * 8 + 4];
            f16x8 a;
            a[0] = (f16)w0.x; a[1] = (f16)w0.y; a[2] = (f16)w0.z; a[3] = (f16)w0.w;
            a[4] = (f16)w1.x; a[5] = (f16)w1.y; a[6] = (f16)w1.z; a[7] = (f16)w1.w;
            A[s] = a;
        }
    }

    f4 acc[8] = {};
    for (int ph = 0; ph < 2; ++ph) {
        __syncthreads();
#pragma unroll
        for (int i = 0; i < 16; ++i) {
            int id = i * 256 + t;
            int r = id >> 5, s8 = id & 31;
            f4 x0 = *(const f4*)&X[(size_t)(m0g + r) * 512 + ph * 256 + s8 * 8];
            f4 x1 = *(const f4*)&X[(size_t)(m0g + r) * 512 + ph * 256 + s8 * 8 + 4];
            f16x8 v;
            v[0] = (f16)x0.x; v[1] = (f16)x0.y; v[2] = (f16)x0.z; v[3] = (f16)x0.w;
            v[4] = (f16)x1.x; v[5] = (f16)x1.y; v[6] = (f16)x1.z; v[7] = (f16)x1.w;
            int sl = (s8 & 16) | ((s8 ^ r) & 15);
            *(f16x8*)&Xs[r][sl * 8] = v;
        }
        __syncthreads();
#pragma unroll
        for (int s = 0; s < 8; ++s) {
            const f16x8 a = A[ph * 8 + s];
#pragma unroll
            for (int jt = 0; jt < 8; ++jt) {
                int rr = jt * 16 + lo;
                int c8 = s * 4 + h;
                int sl = (c8 & 16) | ((c8 ^ rr) & 15);
                f16x8 bb = *(const f16x8*)&Xs[rr][sl * 8];
                acc[jt] = __builtin_amdgcn_mfma_f32_16x16x32_f16(a, bb, acc[jt], 0, 0, 0);
            }
        }
    }
#pragma unroll
    for (int jt = 0; jt < 8; ++jt)
#pragma unroll
        for (int r = 0; r < 4; ++r) {
            int e = e0 + wave * 16 + h * 4 + r;
            int m = ml + jt * 16 + lo;
            VT[((size_t)b * 512 + e) * 4096 + m] = (bf16)acc[jt][r];
        }
}

// ---------------------------------------------------------------------------
// K2 (proven): wave-per-row fp64 normalize -> fp32 qn + fp16 qh.
// ---------------------------------------------------------------------------
__global__ __launch_bounds__(256) void norm_q(const double* __restrict__ Q,
                                              float* __restrict__ QF,
                                              f16* __restrict__ QH) {
    const int wave = threadIdx.x >> 6, lane = threadIdx.x & 63;
    const int row = blockIdx.x * 4 + wave;
    const double* q = Q + (size_t)row * 512;
    double x[8];
    double s = 0.0;
    for (int j = 0; j < 8; ++j) { x[j] = q[lane * 8 + j]; s += x[j] * x[j]; }
    for (int off = 1; off < 64; off <<= 1) s += __shfl_xor(s, off);
    double nm = fmax(sqrt(s), 1e-12);
    for (int j = 0; j < 8; ++j) {
        float qf = (float)(x[j] / nm);
        QF[(size_t)row * 512 + lane * 8 + j] = qf;
        QH[(size_t)row * 512 + lane * 8 + j] = (f16)qf;
    }
}

// ---------------------------------------------------------------------------
// K3 (R11, proven): 1-term fp16 MFMA cosine + narrow-band fp32 verify.
// ---------------------------------------------------------------------------
__global__ __launch_bounds__(512) void qk_mfma(const float* __restrict__ QF,
                                               const f16* __restrict__ QHB,
                                               uint16_t* __restrict__ counts,
                                               uint16_t* __restrict__ idxs,
                                               bf16* __restrict__ vals) {
    __shared__ f16 Bs[2][128][128];       // 64 KB, slot-swizzled
    __shared__ int cnt[128];
    __shared__ int bcnt;
    __shared__ uint32_t blist[BCAPC];     // 2 KB

    const int t = threadIdx.x;
    const int wave = t >> 6, lane = t & 63;
    const int ln16 = lane & 15, hi4 = lane >> 4;
    const int rg = wave >> 1, mg = wave & 1;
    const int grp = blockIdx.x & 7;            // one (batch,half) per XCD
    const int b = grp >> 1, half = grp & 1;
    const int n0 = (blockIdx.x >> 3) * 128;
    const size_t nb = (size_t)b * 4096;
    const float* qf = QF + nb * 512;
    const f16* qh = QHB + nb * 512;
    const int mbase = half * 2048;

    f16x8 A[2][16];
#pragma unroll
    for (int rt = 0; rt < 2; ++rt) {
        const size_t arow = (size_t)(n0 + rg * 32 + rt * 16 + ln16) * 512;
#pragma unroll
        for (int s = 0; s < 16; ++s)
            A[rt][s] = *(const f16x8*)&qh[arow + s * 32 + hi4 * 8];
    }

    if (t < 128) cnt[t] = 0;
    if (t == 0) bcnt = 0;

#pragma unroll
    for (int i = 0; i < 4; ++i) {
        int id = i * 512 + t, r = id >> 4, s = id & 15;
        *(f16x8*)&Bs[0][r][(s ^ (r & 15)) * 8] =
            *(const f16x8*)&qh[(size_t)(mbase + r) * 512 + s * 8];
    }
    __syncthreads();

    for (int ch = 0; ch < 16; ++ch) {
        const int mst = mbase + ch * 128;
        f4 S[2][4] = {};
#pragma unroll
        for (int k0i = 0; k0i < 4; ++k0i) {
            const int buf = k0i & 1;
            const bool last = (k0i == 3) && (ch == 15);
            const int nmst = (k0i < 3) ? mst : mst + 128;
            const int nk0 = (k0i < 3) ? (k0i + 1) * 128 : 0;
            f16x8 L[4];
            if (!last) {                        // issue next-step loads EARLY
#pragma unroll
                for (int i = 0; i < 4; ++i) {
                    int id = i * 512 + t, r = id >> 4, s = id & 15;
                    L[i] = *(const f16x8*)&qh[(size_t)(nmst + r) * 512 + nk0 + s * 8];
                }
            }
#pragma unroll
            for (int kk = 0; kk < 4; ++kk) {
                const int s = k0i * 4 + kk;
                const f16x8 a0 = A[0][s], a1 = A[1][s];
#pragma unroll
                for (int tt = 0; tt < 4; ++tt) {
                    const int br = mg * 64 + tt * 16 + ln16;
                    f16x8 bb = *(const f16x8*)&Bs[buf][br][((kk * 4 + hi4) ^ ln16) * 8];
                    S[0][tt] = __builtin_amdgcn_mfma_f32_16x16x32_f16(a0, bb, S[0][tt], 0, 0, 0);
                    S[1][tt] = __builtin_amdgcn_mfma_f32_16x16x32_f16(a1, bb, S[1][tt], 0, 0, 0);
                }
            }
            if (k0i == 3) {                     // chunk complete: threshold
#pragma unroll
                for (int rt = 0; rt < 2; ++rt)
#pragma unroll
                    for (int tt = 0; tt < 4; ++tt) {
                        const int m = mst + mg * 64 + tt * 16 + ln16;
#pragma unroll
                        for (int i = 0; i < 4; ++i) {
                            float cs = S[rt][tt][i];
                            int row = rg * 32 + rt * 16 + hi4 * 4 + i;
                            if (cs > 0.1f + QBAND) {
                                int pos = atomicAdd(&cnt[row], 1);
                                if (pos < CAP2) {
                                    size_t o = ((size_t)(nb + n0 + row) * 2 + half) * CAP2 + pos;
                                    idxs[o] = (uint16_t)m;
                                    vals[o] = (bf16)cs;
                                }
                            } else if (cs > 0.1f - QBAND) {
                                int bp = atomicAdd(&bcnt, 1);
                                if (bp < BCAPC)
                                    blist[bp] = ((uint32_t)row << 12) | (uint32_t)m;
                            }
                        }
                    }
            }
            __syncthreads();           // Bs[buf^1] reads done; blist complete
            if (!last) {
#pragma unroll
                for (int i = 0; i < 4; ++i) {
                    int id = i * 512 + t, r = id >> 4, s = id & 15;
                    *(f16x8*)&Bs[buf ^ 1][r][(s ^ (r & 15)) * 8] = L[i];
                }
            }
            if (k0i == 3) {            // wave-parallel fp32/f64-acc verify
                int nbd = bcnt; if (nbd > BCAPC) nbd = BCAPC;
                for (int p = wave; p < nbd; p += 8) {
                    uint32_t pk = blist[p];
                    int row = (int)(pk >> 12), m = (int)(pk & 4095);
                    const float* qa = qf + (size_t)(n0 + row) * 512;
                    const float* qc = qf + (size_t)m * 512;
                    f4 a0 = *(const f4*)&qa[lane * 8];
                    f4 a1 = *(const f4*)&qa[lane * 8 + 4];
                    f4 c0 = *(const f4*)&qc[lane * 8];
                    f4 c1 = *(const f4*)&qc[lane * 8 + 4];
                    double s = (double)a0.x * c0.x + (double)a0.y * c0.y +
                               (double)a0.z * c0.z + (double)a0.w * c0.w +
                               (double)a1.x * c1.x + (double)a1.y * c1.y +
                               (double)a1.z * c1.z + (double)a1.w * c1.w;
                    for (int off = 1; off < 64; off <<= 1) s += __shfl_xor(s, off);
                    if (lane == 0 && s > 0.1) {
                        int pos = atomicAdd(&cnt[row], 1);
                        if (pos < CAP2) {
                            size_t o = ((size_t)(nb + n0 + row) * 2 + half) * CAP2 + pos;
                            idxs[o] = (uint16_t)m;
                            vals[o] = (bf16)(float)s;
                        }
                    }
                }
            }
            __syncthreads();           // staging writes visible; verify done
            if (k0i == 3 && t == 0) bcnt = 0;
        }
    }
    __syncthreads();
    if (t < 128) {
        int c = cnt[t];
        counts[(size_t)(nb + n0 + t) * 2 + half] = (uint16_t)(c > CAP2 ? CAP2 : c);
    }
}

// ---------------------------------------------------------------------------
// K4 (R10, proven): 32x32x16-MFMA PV + fused LayerNorm. grid 256, 512 thr.
// ---------------------------------------------------------------------------
__global__ __launch_bounds__(512, 2) void pv_mfma(const bf16* __restrict__ VT,
                                                  const uint16_t* __restrict__ counts,
                                                  const uint16_t* __restrict__ idxs,
                                                  const bf16* __restrict__ vals,
                                                  const float* __restrict__ gamma,
                                                  const float* __restrict__ beta,
                                                  float* __restrict__ Out) {
    __shared__ __align__(16) char smemraw[147456];   // Vts 128K + Wsm 16K
    bf16 (*Vts)[128] = (bf16(*)[128])smemraw;        // [512 e][128 m] swz
    bf16 (*Wsm)[128] = (bf16(*)[128])(smemraw + 131072); // [64 n][128 m] swz

    const int t = threadIdx.x;
    const int wave = t >> 6, lane = t & 63;
    const int l31 = lane & 31, l15 = lane & 15, g = lane >> 5;
    const int grp = blockIdx.x & 7;                  // XCD-pinned batch panel
    const int b = grp >> 1;
    const int n0 = ((blockIdx.x >> 3) + ((grp & 1) ? 32 : 0)) * 64;
    const size_t nb = (size_t)b * 4096;
    const bf16* vtb = VT + (size_t)b * 512 * 4096;

    int myc0 = 0, myc1 = 0, cu = 0, pb = 0;
    u16x8 pi0 = {}, pi1 = {};
    bf16x8 pv0 = {}, pv1 = {};
    size_t base0 = 0, base1 = 0;
    if (t < 64) {
        myc0 = (int)counts[(size_t)(nb + n0 + t) * 2 + 0];
        myc1 = (int)counts[(size_t)(nb + n0 + t) * 2 + 1];
        if (myc0 > CAP2) myc0 = CAP2;
        if (myc1 > CAP2) myc1 = CAP2;
        base0 = ((size_t)(nb + n0 + t) * 2 + 0) * CAP2;
        base1 = ((size_t)(nb + n0 + t) * 2 + 1) * CAP2;
        pi0 = *(const u16x8*)&idxs[base0];
        pi1 = *(const u16x8*)&idxs[base0 + 8];
        pv0 = *(const bf16x8*)&vals[base0];
        pv1 = *(const bf16x8*)&vals[base0 + 8];
    }

    bf16x8 L[16];
#pragma unroll
    for (int i = 0; i < 16; ++i) {
        int id = i * 512 + t, r = id >> 4, s = id & 15;
        L[i] = *(const bf16x8*)&vtb[(size_t)r * 4096 + s * 8];
    }

    f16v acc[2][2] = {};   // [nt][et]

    for (int ch = 0; ch < 32; ++ch) {
        __syncthreads();
#pragma unroll
        for (int i = 0; i < 16; ++i) {
            int id = i * 512 + t, r = id >> 4, s = id & 15;
            *(bf16x8*)&Vts[r][(s ^ (r & 15)) << 3] = L[i];
        }
        if (t < 64) {
            bf16 z0 = (bf16)0.0f;
            bf16x8 zv = {z0, z0, z0, z0, z0, z0, z0, z0};
#pragma unroll
            for (int sj = 0; sj < 16; ++sj) *(bf16x8*)&Wsm[t][sj * 8] = zv;
            if (ch == 16) cu = 0;
            const int m0l = ch * 128;
            const int myc = (ch >= 16) ? myc1 : myc0;
            const size_t base = (ch >= 16) ? base1 : base0;
            int end = cu;
#pragma unroll
            for (int j = 0; j < 16; ++j) {
                int pos = pb + j;
                int mi = (j < 8) ? (int)pi0[j] : (int)pi1[j - 8];
                bf16 vv = (j < 8) ? pv0[j] : pv1[j - 8];
                if (pos == end && pos < myc && mi < m0l + 128) {
                    int lo = mi - m0l;
                    Wsm[t][(((lo >> 3) ^ (t & 15)) << 3) | (lo & 7)] = vv;
                    end = pos + 1;
                }
            }
            if (end == pb + 16) {
                while (end < myc) {
                    int mi = (int)idxs[base + end];
                    if (mi >= m0l + 128) break;
                    int lo = mi - m0l;
                    Wsm[t][(((lo >> 3) ^ (t & 15)) << 3) | (lo & 7)] =
                        vals[base + end];
                    ++end;
                }
            }
            cu = end;
        }
        __syncthreads();
        if (ch < 31) {
            const int mo = (ch + 1) * 128;
#pragma unroll
            for (int i = 0; i < 16; ++i) {
                int id = i * 512 + t, r = id >> 4, s = id & 15;
                L[i] = *(const bf16x8*)&vtb[(size_t)r * 4096 + mo + s * 8];
            }
            if (t < 64) {
                int ncu = (ch + 1 == 16) ? 0 : cu;
                const size_t nbase = (ch + 1 >= 16) ? base1 : base0;
                pb = ncu & ~7;
                pi0 = *(const u16x8*)&idxs[nbase + pb];
                pi1 = *(const u16x8*)&idxs[nbase + pb + 8];
                pv0 = *(const bf16x8*)&vals[nbase + pb];
                pv1 = *(const bf16x8*)&vals[nbase + pb + 8];
            }
        }
#pragma unroll
        for (int ks = 0; ks < 8; ++ks) {
            const int sw = (((ks * 2 + g) ^ l15) << 3);
            bf16x8 A0 = *(const bf16x8*)&Wsm[l31][sw];
            bf16x8 A1 = *(const bf16x8*)&Wsm[32 + l31][sw];
            bf16x8 B0 = *(const bf16x8*)&Vts[wave * 64 + l31][sw];
            bf16x8 B1 = *(const bf16x8*)&Vts[wave * 64 + 32 + l31][sw];
            acc[0][0] = __builtin_amdgcn_mfma_f32_32x32x16_bf16(A0, B0, acc[0][0], 0, 0, 0);
            acc[0][1] = __builtin_amdgcn_mfma_f32_32x32x16_bf16(A0, B1, acc[0][1], 0, 0, 0);
            acc[1][0] = __builtin_amdgcn_mfma_f32_32x32x16_bf16(A1, B0, acc[1][0], 0, 0, 0);
            acc[1][1] = __builtin_amdgcn_mfma_f32_32x32x16_bf16(A1, B1, acc[1][1], 0, 0, 0);
        }
    }

    // ---- fused LayerNorm over 512 cols ----
    __syncthreads();
    float* red = (float*)smemraw;            // [8][64][2]
    float* mrs = (float*)(smemraw + 4096);   // mu[64], rs[64]
#pragma unroll
    for (int nt = 0; nt < 2; ++nt)
#pragma unroll
        for (int r = 0; r < 16; ++r) {
            float v0 = acc[nt][0][r], v1 = acc[nt][1][r];
            float s = v0 + v1, q = v0 * v0 + v1 * v1;
            for (int off = 1; off < 32; off <<= 1) {
                s += __shfl_xor(s, off);
                q += __shfl_xor(q, off);
            }
            if (l31 == 0) {
                int nloc = nt * 32 + (r & 3) + 8 * (r >> 2) + 4 * g;
                red[(wave * 64 + nloc) * 2] = s;
                red[(wave * 64 + nloc) * 2 + 1] = q;
            }
        }
    __syncthreads();
    if (t < 64) {
        float s = 0.f, q = 0.f;
        for (int w2 = 0; w2 < 8; ++w2) {
            s += red[(w2 * 64 + t) * 2];
            q += red[(w2 * 64 + t) * 2 + 1];
        }
        float mu = s * (1.0f / 512.0f);
        float var = q * (1.0f / 512.0f) - mu * mu;
        mrs[t] = mu;
        mrs[64 + t] = rsqrtf(var + 1e-5f);
    }
    __syncthreads();
    const float g0 = gamma[wave * 64 + l31], g1 = gamma[wave * 64 + 32 + l31];
    const float b0 = beta[wave * 64 + l31], b1 = beta[wave * 64 + 32 + l31];
#pragma unroll
    for (int nt = 0; nt < 2; ++nt)
#pragma unroll
        for (int r = 0; r < 16; ++r) {
            int nloc = nt * 32 + (r & 3) + 8 * (r >> 2) + 4 * g;
            float mu = mrs[nloc], rs = mrs[64 + nloc];
            size_t ro = (nb + n0 + nloc) * 512;
            float y0 = (acc[nt][0][r] - mu) * rs * g0 + b0;
            float y1 = (acc[nt][1][r] - mu) * rs * g1 + b1;
            Out[ro + wave * 64 + l31] = y0;
            Out[ro + wave * 64 + 32 + l31] = y1;
        }
}

// ---------------------------------------------------------------------------
extern "C" void kernel_launch(void* const* d_in, const int* in_sizes, int n_in,
                              void* d_out, int out_size, void* d_ws, size_t ws_size,
                              hipStream_t stream) {
    const float* x     = (const float*)d_in[0];
    const float* wqk   = (const float*)d_in[1];
    const float* wv    = (const float*)d_in[2];
    const float* gamma = (const float*)d_in[3];
    const float* beta  = (const float*)d_in[4];
    float* out = (float*)d_out;

    char* ws = (char*)d_ws;
    // fp64 qtmp [0, 67,108,864) dies after norm_q; idxs+vals recycle it EXACTLY.
    uint16_t* idxs   = (uint16_t*)ws;                        // 33,554,432 B
    bf16*     vals   = (bf16*)(ws + 33554432);               // -> 67,108,864
    float*    qn32   = (float*)(ws + 67108864);              // -> 100,663,296
    f16*      qh16   = (f16*)(ws + 100663296);               // -> 117,440,512
    // [117,440,512 .. 134,217,728) dead
    bf16*     vt     = (bf16*)(ws + 134217728);              // -> 150,994,944
    uint16_t* counts = (uint16_t*)(ws + 150994944);          // -> 151,060,480
    double*   qtmp   = (double*)ws;                          // TEMP, dies after norm_q
    const size_t need = 151060480;  // == R2-proven ws_size lower bound
    if (ws_size < need) return;

    proj_f64<<<dim3(128, 4), 256, 0, stream>>>(x, wqk, qtmp);
    proj_v16<<<dim3(128, 8), 256, 0, stream>>>(x, wv, vt);
    norm_q<<<4096, 256, 0, stream>>>(qtmp, qn32, qh16);
    qk_mfma<<<256, 512, 0, stream>>>(qn32, qh16, counts, idxs, vals);
    pv_mfma<<<256, 512, 0, stream>>>(vt, counts, idxs, vals, gamma, beta, out);
}

// Round 12
// 490.049 us; speedup vs baseline: 2.4935x; 1.2870x over previous
//
#include <hip/hip_runtime.h>
#include <hip/hip_bf16.h>
#include <stdint.h>

// SimTransformer — fp32 I/O. R16: R15 with the compile fix (vector lanes
// assigned directly; no references/arrays — R15c's split2(f16&) was illegal
// for ext_vector elements). fp64 Q-GEMM (216us, fp64-pipe-bound) replaced by
// 3-term split-fp16 MFMA with SCALED lo-limbs (l = fp16((x-h)*2048);
// Q = Shh + Smid/2048; cs-level err ~5e-7 << np fp32 jitter ~1e-6).
// proj_v16 / qk_mfma / pv_mfma byte-identical to R14 (proven 630us).

typedef __bf16 bf16;
typedef __bf16 bf16x8 __attribute__((ext_vector_type(8)));
typedef _Float16 f16;
typedef _Float16 f16x8 __attribute__((ext_vector_type(8)));
typedef unsigned short u16x8 __attribute__((ext_vector_type(8)));
typedef float f4 __attribute__((ext_vector_type(4)));
typedef float f16v __attribute__((ext_vector_type(16)));

#define CAP2 512     // per-row per-m-half list cap (mean ~25/half)
#define QBAND 2e-4f  // borderline band around 0.1 (fp16 1-term sigma ~9e-6)
#define BCAPC 512    // borderline pairs per 128-m chunk (mean ~11)

// Split two f4's into hi/lo f16x8 limbs. Direct lane assignment (legal).
#define SPLIT_HL(v0, v1, h, l)                                              \
    do {                                                                    \
        h[0] = (f16)v0.x; l[0] = (f16)((v0.x - (float)h[0]) * 2048.0f);     \
        h[1] = (f16)v0.y; l[1] = (f16)((v0.y - (float)h[1]) * 2048.0f);     \
        h[2] = (f16)v0.z; l[2] = (f16)((v0.z - (float)h[2]) * 2048.0f);     \
        h[3] = (f16)v0.w; l[3] = (f16)((v0.w - (float)h[3]) * 2048.0f);     \
        h[4] = (f16)v1.x; l[4] = (f16)((v1.x - (float)h[4]) * 2048.0f);     \
        h[5] = (f16)v1.y; l[5] = (f16)((v1.y - (float)h[5]) * 2048.0f);     \
        h[6] = (f16)v1.z; l[6] = (f16)((v1.z - (float)h[6]) * 2048.0f);     \
        h[7] = (f16)v1.w; l[7] = (f16)((v1.w - (float)h[7]) * 2048.0f);     \
    } while (0)

// ---------------------------------------------------------------------------
// K1 (R16): Q[n,e] fp32 = X·W^T via 3-term split-fp16 MFMA. 64n/block,
// 4 e-chunks of 128. A = X-row hi+lo in regs; B = W hi/lo double-buffered
// XOR-swizzled LDS (128 KB); early-issued staging loads.
// ---------------------------------------------------------------------------
__global__ __launch_bounds__(512) void proj_q16(const float* __restrict__ X,
                                                const float* __restrict__ W,
                                                float* __restrict__ Q) {
    __shared__ f16 Bh[2][128][128];   // 64 KB
    __shared__ f16 Bl[2][128][128];   // 64 KB
    const int t = threadIdx.x;
    const int wave = t >> 6, lane = t & 63;
    const int ln16 = lane & 15, hi4 = lane >> 4;
    const int rg = wave >> 1, mg = wave & 1;
    const int n0 = blockIdx.x * 64;

    // A: X row n0 + rg*16 + ln16; slice s -> k = s*32 + hi4*8
    f16x8 Ah[16], Al[16];
    {
        const size_t arow = (size_t)(n0 + rg * 16 + ln16) * 512;
#pragma unroll
        for (int s = 0; s < 16; ++s) {
            f4 x0 = *(const f4*)&X[arow + s * 32 + hi4 * 8];
            f4 x1 = *(const f4*)&X[arow + s * 32 + hi4 * 8 + 4];
            f16x8 h, l;
            SPLIT_HL(x0, x1, h, l);
            Ah[s] = h; Al[s] = l;
        }
    }

    // prologue: stage (e-chunk 0, k0 0) into buf 0
#pragma unroll
    for (int i = 0; i < 4; ++i) {
        int id = i * 512 + t, r = id >> 4, s = id & 15;
        f4 w0 = *(const f4*)&W[(size_t)r * 512 + s * 8];
        f4 w1 = *(const f4*)&W[(size_t)r * 512 + s * 8 + 4];
        f16x8 h, l;
        SPLIT_HL(w0, w1, h, l);
        *(f16x8*)&Bh[0][r][(s ^ (r & 15)) * 8] = h;
        *(f16x8*)&Bl[0][r][(s ^ (r & 15)) * 8] = l;
    }
    __syncthreads();

    for (int ch = 0; ch < 4; ++ch) {
        const int eb = ch * 128;
        f4 Shh[4] = {}, Smid[4] = {};
#pragma unroll
        for (int k0i = 0; k0i < 4; ++k0i) {
            const int buf = k0i & 1;
            const bool last = (ch == 3) && (k0i == 3);
            const int neb = (k0i < 3) ? eb : eb + 128;
            const int nkb = (k0i < 3) ? (k0i + 1) * 128 : 0;
            f4 Lw[8];
            if (!last) {                        // issue next-stage loads EARLY
#pragma unroll
                for (int i = 0; i < 4; ++i) {
                    int id = i * 512 + t, r = id >> 4, s = id & 15;
                    Lw[i * 2]     = *(const f4*)&W[(size_t)(neb + r) * 512 + nkb + s * 8];
                    Lw[i * 2 + 1] = *(const f4*)&W[(size_t)(neb + r) * 512 + nkb + s * 8 + 4];
                }
            }
#pragma unroll
            for (int kk = 0; kk < 4; ++kk) {
                const int s = k0i * 4 + kk;
                const f16x8 ah = Ah[s], al = Al[s];
#pragma unroll
                for (int tt = 0; tt < 4; ++tt) {
                    const int br = mg * 64 + tt * 16 + ln16;
                    const int sl = ((kk * 4 + hi4) ^ ln16) * 8;
                    f16x8 bh = *(const f16x8*)&Bh[buf][br][sl];
                    f16x8 bl = *(const f16x8*)&Bl[buf][br][sl];
                    Shh[tt]  = __builtin_amdgcn_mfma_f32_16x16x32_f16(ah, bh, Shh[tt], 0, 0, 0);
                    Smid[tt] = __builtin_amdgcn_mfma_f32_16x16x32_f16(al, bh, Smid[tt], 0, 0, 0);
                    Smid[tt] = __builtin_amdgcn_mfma_f32_16x16x32_f16(ah, bl, Smid[tt], 0, 0, 0);
                }
            }
            __syncthreads();           // all reads of Bs[buf^1] done
            if (!last) {
#pragma unroll
                for (int i = 0; i < 4; ++i) {
                    int id = i * 512 + t, r = id >> 4, s = id & 15;
                    f4 w0 = Lw[i * 2], w1 = Lw[i * 2 + 1];
                    f16x8 h, l;
                    SPLIT_HL(w0, w1, h, l);
                    *(f16x8*)&Bh[buf ^ 1][r][(s ^ (r & 15)) * 8] = h;
                    *(f16x8*)&Bl[buf ^ 1][r][(s ^ (r & 15)) * 8] = l;
                }
            }
            __syncthreads();           // staging writes visible
        }
        // write Q chunk (combine limbs)
#pragma unroll
        for (int tt = 0; tt < 4; ++tt) {
            const int ecol = eb + mg * 64 + tt * 16 + ln16;
#pragma unroll
            for (int i = 0; i < 4; ++i)
                Q[(size_t)(n0 + rg * 16 + hi4 * 4 + i) * 512 + ecol] =
                    Shh[tt][i] + Smid[tt][i] * (1.0f / 2048.0f);
        }
    }
}

// ---------------------------------------------------------------------------
// K1b (proven R13): VT[b][e][m] = (X Wv^T)[m,e] via fp16 MFMA.
// ---------------------------------------------------------------------------
__global__ __launch_bounds__(256) void proj_v16(const float* __restrict__ X,
                                                const float* __restrict__ W,
                                                bf16* __restrict__ VT) {
    __shared__ f16 Xs[128][256];   // 64 KB, slot-swizzled
    const int t = threadIdx.x;
    const int wave = t >> 6, lane = t & 63;
    const int lo = lane & 15, h = lane >> 4;
    const int m0g = blockIdx.x * 128;
    const int e0 = blockIdx.y * 64;
    const int b = m0g >> 12, ml = m0g & 4095;

    f16x8 A[16];
    {
        const size_t arow = (size_t)(e0 + wave * 16 + lo) * 512;
#pragma unroll
        for (int s = 0; s < 16; ++s) {
            f4 w0 = *(const f4*)&W[arow + s * 32 + h * 8];
            f4 w1 = *(const f4*)&W[arow + s * 32 + h * 8 + 4];
            f16x8 a;
            a[0] = (f16)w0.x; a[1] = (f16)w0.y; a[2] = (f16)w0.z; a[3] = (f16)w0.w;
            a[4] = (f16)w1.x; a[5] = (f16)w1.y; a[6] = (f16)w1.z; a[7] = (f16)w1.w;
            A[s] = a;
        }
    }

    f4 acc[8] = {};
    for (int ph = 0; ph < 2; ++ph) {
        __syncthreads();
#pragma unroll
        for (int i = 0; i < 16; ++i) {
            int id = i * 256 + t;
            int r = id >> 5, s8 = id & 31;
            f4 x0 = *(const f4*)&X[(size_t)(m0g + r) * 512 + ph * 256 + s8 * 8];
            f4 x1 = *(const f4*)&X[(size_t)(m0g + r) * 512 + ph * 256 + s8 * 8 + 4];
            f16x8 v;
            v[0] = (f16)x0.x; v[1] = (f16)x0.y; v[2] = (f16)x0.z; v[3] = (f16)x0.w;
            v[4] = (f16)x1.x; v[5] = (f16)x1.y; v[6] = (f16)x1.z; v[7] = (f16)x1.w;
            int sl = (s8 & 16) | ((s8 ^ r) & 15);
            *(f16x8*)&Xs[r][sl * 8] = v;
        }
        __syncthreads();
#pragma unroll
        for (int s = 0; s < 8; ++s) {
            const f16x8 a = A[ph * 8 + s];
#pragma unroll
            for (int jt = 0; jt < 8; ++jt) {
                int rr = jt * 16 + lo;
                int c8 = s * 4 + h;
                int sl = (c8 & 16) | ((c8 ^ rr) & 15);
                f16x8 bb = *(const f16x8*)&Xs[rr][sl * 8];
                acc[jt] = __builtin_amdgcn_mfma_f32_16x16x32_f16(a, bb, acc[jt], 0, 0, 0);
            }
        }
    }
#pragma unroll
    for (int jt = 0; jt < 8; ++jt)
#pragma unroll
        for (int r = 0; r < 4; ++r) {
            int e = e0 + wave * 16 + h * 4 + r;
            int m = ml + jt * 16 + lo;
            VT[((size_t)b * 512 + e) * 4096 + m] = (bf16)acc[jt][r];
        }
}

// ---------------------------------------------------------------------------
// K2 (R16): wave-per-row normalize, fp32 Q IN-PLACE (fp64 accumulation),
// + fp16 qh. Per-thread read-then-write: no aliasing.
// ---------------------------------------------------------------------------
__global__ __launch_bounds__(256) void norm_q(float* __restrict__ Q,
                                              f16* __restrict__ QH) {
    const int wave = threadIdx.x >> 6, lane = threadIdx.x & 63;
    const int row = blockIdx.x * 4 + wave;
    float* q = Q + (size_t)row * 512;
    float x[8];
    double s = 0.0;
    for (int j = 0; j < 8; ++j) { x[j] = q[lane * 8 + j]; s += (double)x[j] * x[j]; }
    for (int off = 1; off < 64; off <<= 1) s += __shfl_xor(s, off);
    double nm = fmax(sqrt(s), 1e-12);
    for (int j = 0; j < 8; ++j) {
        float qf = (float)((double)x[j] / nm);
        q[lane * 8 + j] = qf;
        QH[(size_t)row * 512 + lane * 8 + j] = (f16)qf;
    }
}

// ---------------------------------------------------------------------------
// K3 (R11, proven): 1-term fp16 MFMA cosine + narrow-band fp32 verify.
// ---------------------------------------------------------------------------
__global__ __launch_bounds__(512) void qk_mfma(const float* __restrict__ QF,
                                               const f16* __restrict__ QHB,
                                               uint16_t* __restrict__ counts,
                                               uint16_t* __restrict__ idxs,
                                               bf16* __restrict__ vals) {
    __shared__ f16 Bs[2][128][128];       // 64 KB, slot-swizzled
    __shared__ int cnt[128];
    __shared__ int bcnt;
    __shared__ uint32_t blist[BCAPC];     // 2 KB

    const int t = threadIdx.x;
    const int wave = t >> 6, lane = t & 63;
    const int ln16 = lane & 15, hi4 = lane >> 4;
    const int rg = wave >> 1, mg = wave & 1;
    const int grp = blockIdx.x & 7;            // one (batch,half) per XCD
    const int b = grp >> 1, half = grp & 1;
    const int n0 = (blockIdx.x >> 3) * 128;
    const size_t nb = (size_t)b * 4096;
    const float* qf = QF + nb * 512;
    const f16* qh = QHB + nb * 512;
    const int mbase = half * 2048;

    f16x8 A[2][16];
#pragma unroll
    for (int rt = 0; rt < 2; ++rt) {
        const size_t arow = (size_t)(n0 + rg * 32 + rt * 16 + ln16) * 512;
#pragma unroll
        for (int s = 0; s < 16; ++s)
            A[rt][s] = *(const f16x8*)&qh[arow + s * 32 + hi4 * 8];
    }

    if (t < 128) cnt[t] = 0;
    if (t == 0) bcnt = 0;

#pragma unroll
    for (int i = 0; i < 4; ++i) {
        int id = i * 512 + t, r = id >> 4, s = id & 15;
        *(f16x8*)&Bs[0][r][(s ^ (r & 15)) * 8] =
            *(const f16x8*)&qh[(size_t)(mbase + r) * 512 + s * 8];
    }
    __syncthreads();

    for (int ch = 0; ch < 16; ++ch) {
        const int mst = mbase + ch * 128;
        f4 S[2][4] = {};
#pragma unroll
        for (int k0i = 0; k0i < 4; ++k0i) {
            const int buf = k0i & 1;
            const bool last = (k0i == 3) && (ch == 15);
            const int nmst = (k0i < 3) ? mst : mst + 128;
            const int nk0 = (k0i < 3) ? (k0i + 1) * 128 : 0;
            f16x8 L[4];
            if (!last) {                        // issue next-step loads EARLY
#pragma unroll
                for (int i = 0; i < 4; ++i) {
                    int id = i * 512 + t, r = id >> 4, s = id & 15;
                    L[i] = *(const f16x8*)&qh[(size_t)(nmst + r) * 512 + nk0 + s * 8];
                }
            }
#pragma unroll
            for (int kk = 0; kk < 4; ++kk) {
                const int s = k0i * 4 + kk;
                const f16x8 a0 = A[0][s], a1 = A[1][s];
#pragma unroll
                for (int tt = 0; tt < 4; ++tt) {
                    const int br = mg * 64 + tt * 16 + ln16;
                    f16x8 bb = *(const f16x8*)&Bs[buf][br][((kk * 4 + hi4) ^ ln16) * 8];
                    S[0][tt] = __builtin_amdgcn_mfma_f32_16x16x32_f16(a0, bb, S[0][tt], 0, 0, 0);
                    S[1][tt] = __builtin_amdgcn_mfma_f32_16x16x32_f16(a1, bb, S[1][tt], 0, 0, 0);
                }
            }
            if (k0i == 3) {                     // chunk complete: threshold
#pragma unroll
                for (int rt = 0; rt < 2; ++rt)
#pragma unroll
                    for (int tt = 0; tt < 4; ++tt) {
                        const int m = mst + mg * 64 + tt * 16 + ln16;
#pragma unroll
                        for (int i = 0; i < 4; ++i) {
                            float cs = S[rt][tt][i];
                            int row = rg * 32 + rt * 16 + hi4 * 4 + i;
                            if (cs > 0.1f + QBAND) {
                                int pos = atomicAdd(&cnt[row], 1);
                                if (pos < CAP2) {
                                    size_t o = ((size_t)(nb + n0 + row) * 2 + half) * CAP2 + pos;
                                    idxs[o] = (uint16_t)m;
                                    vals[o] = (bf16)cs;
                                }
                            } else if (cs > 0.1f - QBAND) {
                                int bp = atomicAdd(&bcnt, 1);
                                if (bp < BCAPC)
                                    blist[bp] = ((uint32_t)row << 12) | (uint32_t)m;
                            }
                        }
                    }
            }
            __syncthreads();           // Bs[buf^1] reads done; blist complete
            if (!last) {
#pragma unroll
                for (int i = 0; i < 4; ++i) {
                    int id = i * 512 + t, r = id >> 4, s = id & 15;
                    *(f16x8*)&Bs[buf ^ 1][r][(s ^ (r & 15)) * 8] = L[i];
                }
            }
            if (k0i == 3) {            // wave-parallel fp32/f64-acc verify
                int nbd = bcnt; if (nbd > BCAPC) nbd = BCAPC;
                for (int p = wave; p < nbd; p += 8) {
                    uint32_t pk = blist[p];
                    int row = (int)(pk >> 12), m = (int)(pk & 4095);
                    const float* qa = qf + (size_t)(n0 + row) * 512;
                    const float* qc = qf + (size_t)m * 512;
                    f4 a0 = *(const f4*)&qa[lane * 8];
                    f4 a1 = *(const f4*)&qa[lane * 8 + 4];
                    f4 c0 = *(const f4*)&qc[lane * 8];
                    f4 c1 = *(const f4*)&qc[lane * 8 + 4];
                    double s = (double)a0.x * c0.x + (double)a0.y * c0.y +
                               (double)a0.z * c0.z + (double)a0.w * c0.w +
                               (double)a1.x * c1.x + (double)a1.y * c1.y +
                               (double)a1.z * c1.z + (double)a1.w * c1.w;
                    for (int off = 1; off < 64; off <<= 1) s += __shfl_xor(s, off);
                    if (lane == 0 && s > 0.1) {
                        int pos = atomicAdd(&cnt[row], 1);
                        if (pos < CAP2) {
                            size_t o = ((size_t)(nb + n0 + row) * 2 + half) * CAP2 + pos;
                            idxs[o] = (uint16_t)m;
                            vals[o] = (bf16)(float)s;
                        }
                    }
                }
            }
            __syncthreads();           // staging writes visible; verify done
            if (k0i == 3 && t == 0) bcnt = 0;
        }
    }
    __syncthreads();
    if (t < 128) {
        int c = cnt[t];
        counts[(size_t)(nb + n0 + t) * 2 + half] = (uint16_t)(c > CAP2 ? CAP2 : c);
    }
}

// ---------------------------------------------------------------------------
// K4 (R10, proven): 32x32x16-MFMA PV + fused LayerNorm. grid 256, 512 thr.
// ---------------------------------------------------------------------------
__global__ __launch_bounds__(512, 2) void pv_mfma(const bf16* __restrict__ VT,
                                                  const uint16_t* __restrict__ counts,
                                                  const uint16_t* __restrict__ idxs,
                                                  const bf16* __restrict__ vals,
                                                  const float* __restrict__ gamma,
                                                  const float* __restrict__ beta,
                                                  float* __restrict__ Out) {
    __shared__ __align__(16) char smemraw[147456];   // Vts 128K + Wsm 16K
    bf16 (*Vts)[128] = (bf16(*)[128])smemraw;        // [512 e][128 m] swz
    bf16 (*Wsm)[128] = (bf16(*)[128])(smemraw + 131072); // [64 n][128 m] swz

    const int t = threadIdx.x;
    const int wave = t >> 6, lane = t & 63;
    const int l31 = lane & 31, l15 = lane & 15, g = lane >> 5;
    const int grp = blockIdx.x & 7;                  // XCD-pinned batch panel
    const int b = grp >> 1;
    const int n0 = ((blockIdx.x >> 3) + ((grp & 1) ? 32 : 0)) * 64;
    const size_t nb = (size_t)b * 4096;
    const bf16* vtb = VT + (size_t)b * 512 * 4096;

    int myc0 = 0, myc1 = 0, cu = 0, pb = 0;
    u16x8 pi0 = {}, pi1 = {};
    bf16x8 pv0 = {}, pv1 = {};
    size_t base0 = 0, base1 = 0;
    if (t < 64) {
        myc0 = (int)counts[(size_t)(nb + n0 + t) * 2 + 0];
        myc1 = (int)counts[(size_t)(nb + n0 + t) * 2 + 1];
        if (myc0 > CAP2) myc0 = CAP2;
        if (myc1 > CAP2) myc1 = CAP2;
        base0 = ((size_t)(nb + n0 + t) * 2 + 0) * CAP2;
        base1 = ((size_t)(nb + n0 + t) * 2 + 1) * CAP2;
        pi0 = *(const u16x8*)&idxs[base0];
        pi1 = *(const u16x8*)&idxs[base0 + 8];
        pv0 = *(const bf16x8*)&vals[base0];
        pv1 = *(const bf16x8*)&vals[base0 + 8];
    }

    bf16x8 L[16];
#pragma unroll
    for (int i = 0; i < 16; ++i) {
        int id = i * 512 + t, r = id >> 4, s = id & 15;
        L[i] = *(const bf16x8*)&vtb[(size_t)r * 4096 + s * 8];
    }

    f16v acc[2][2] = {};   // [nt][et]

    for (int ch = 0; ch < 32; ++ch) {
        __syncthreads();
#pragma unroll
        for (int i = 0; i < 16; ++i) {
            int id = i * 512 + t, r = id >> 4, s = id & 15;
            *(bf16x8*)&Vts[r][(s ^ (r & 15)) << 3] = L[i];
        }
        if (t < 64) {
            bf16 z0 = (bf16)0.0f;
            bf16x8 zv = {z0, z0, z0, z0, z0, z0, z0, z0};
#pragma unroll
            for (int sj = 0; sj < 16; ++sj) *(bf16x8*)&Wsm[t][sj * 8] = zv;
            if (ch == 16) cu = 0;
            const int m0l = ch * 128;
            const int myc = (ch >= 16) ? myc1 : myc0;
            const size_t base = (ch >= 16) ? base1 : base0;
            int end = cu;
#pragma unroll
            for (int j = 0; j < 16; ++j) {
                int pos = pb + j;
                int mi = (j < 8) ? (int)pi0[j] : (int)pi1[j - 8];
                bf16 vv = (j < 8) ? pv0[j] : pv1[j - 8];
                if (pos == end && pos < myc && mi < m0l + 128) {
                    int lo = mi - m0l;
                    Wsm[t][(((lo >> 3) ^ (t & 15)) << 3) | (lo & 7)] = vv;
                    end = pos + 1;
                }
            }
            if (end == pb + 16) {
                while (end < myc) {
                    int mi = (int)idxs[base + end];
                    if (mi >= m0l + 128) break;
                    int lo = mi - m0l;
                    Wsm[t][(((lo >> 3) ^ (t & 15)) << 3) | (lo & 7)] =
                        vals[base + end];
                    ++end;
                }
            }
            cu = end;
        }
        __syncthreads();
        if (ch < 31) {
            const int mo = (ch + 1) * 128;
#pragma unroll
            for (int i = 0; i < 16; ++i) {
                int id = i * 512 + t, r = id >> 4, s = id & 15;
                L[i] = *(const bf16x8*)&vtb[(size_t)r * 4096 + mo + s * 8];
            }
            if (t < 64) {
                int ncu = (ch + 1 == 16) ? 0 : cu;
                const size_t nbase = (ch + 1 >= 16) ? base1 : base0;
                pb = ncu & ~7;
                pi0 = *(const u16x8*)&idxs[nbase + pb];
                pi1 = *(const u16x8*)&idxs[nbase + pb + 8];
                pv0 = *(const bf16x8*)&vals[nbase + pb];
                pv1 = *(const bf16x8*)&vals[nbase + pb + 8];
            }
        }
#pragma unroll
        for (int ks = 0; ks < 8; ++ks) {
            const int sw = (((ks * 2 + g) ^ l15) << 3);
            bf16x8 A0 = *(const bf16x8*)&Wsm[l31][sw];
            bf16x8 A1 = *(const bf16x8*)&Wsm[32 + l31][sw];
            bf16x8 B0 = *(const bf16x8*)&Vts[wave * 64 + l31][sw];
            bf16x8 B1 = *(const bf16x8*)&Vts[wave * 64 + 32 + l31][sw];
            acc[0][0] = __builtin_amdgcn_mfma_f32_32x32x16_bf16(A0, B0, acc[0][0], 0, 0, 0);
            acc[0][1] = __builtin_amdgcn_mfma_f32_32x32x16_bf16(A0, B1, acc[0][1], 0, 0, 0);
            acc[1][0] = __builtin_amdgcn_mfma_f32_32x32x16_bf16(A1, B0, acc[1][0], 0, 0, 0);
            acc[1][1] = __builtin_amdgcn_mfma_f32_32x32x16_bf16(A1, B1, acc[1][1], 0, 0, 0);
        }
    }

    // ---- fused LayerNorm over 512 cols ----
    __syncthreads();
    float* red = (float*)smemraw;            // [8][64][2]
    float* mrs = (float*)(smemraw + 4096);   // mu[64], rs[64]
#pragma unroll
    for (int nt = 0; nt < 2; ++nt)
#pragma unroll
        for (int r = 0; r < 16; ++r) {
            float v0 = acc[nt][0][r], v1 = acc[nt][1][r];
            float s = v0 + v1, q = v0 * v0 + v1 * v1;
            for (int off = 1; off < 32; off <<= 1) {
                s += __shfl_xor(s, off);
                q += __shfl_xor(q, off);
            }
            if (l31 == 0) {
                int nloc = nt * 32 + (r & 3) + 8 * (r >> 2) + 4 * g;
                red[(wave * 64 + nloc) * 2] = s;
                red[(wave * 64 + nloc) * 2 + 1] = q;
            }
        }
    __syncthreads();
    if (t < 64) {
        float s = 0.f, q = 0.f;
        for (int w2 = 0; w2 < 8; ++w2) {
            s += red[(w2 * 64 + t) * 2];
            q += red[(w2 * 64 + t) * 2 + 1];
        }
        float mu = s * (1.0f / 512.0f);
        float var = q * (1.0f / 512.0f) - mu * mu;
        mrs[t] = mu;
        mrs[64 + t] = rsqrtf(var + 1e-5f);
    }
    __syncthreads();
    const float g0 = gamma[wave * 64 + l31], g1 = gamma[wave * 64 + 32 + l31];
    const float b0 = beta[wave * 64 + l31], b1 = beta[wave * 64 + 32 + l31];
#pragma unroll
    for (int nt = 0; nt < 2; ++nt)
#pragma unroll
        for (int r = 0; r < 16; ++r) {
            int nloc = nt * 32 + (r & 3) + 8 * (r >> 2) + 4 * g;
            float mu = mrs[nloc], rs = mrs[64 + nloc];
            size_t ro = (nb + n0 + nloc) * 512;
            float y0 = (acc[nt][0][r] - mu) * rs * g0 + b0;
            float y1 = (acc[nt][1][r] - mu) * rs * g1 + b1;
            Out[ro + wave * 64 + l31] = y0;
            Out[ro + wave * 64 + 32 + l31] = y1;
        }
}

// ---------------------------------------------------------------------------
extern "C" void kernel_launch(void* const* d_in, const int* in_sizes, int n_in,
                              void* d_out, int out_size, void* d_ws, size_t ws_size,
                              hipStream_t stream) {
    const float* x     = (const float*)d_in[0];
    const float* wqk   = (const float*)d_in[1];
    const float* wv    = (const float*)d_in[2];
    const float* gamma = (const float*)d_in[3];
    const float* beta  = (const float*)d_in[4];
    float* out = (float*)d_out;

    char* ws = (char*)d_ws;
    uint16_t* idxs   = (uint16_t*)ws;                        // 33,554,432 B
    bf16*     vals   = (bf16*)(ws + 33554432);               // -> 67,108,864
    float*    qn32   = (float*)(ws + 67108864);              // -> 100,663,296 (Q fp32, normalized in-place)
    f16*      qh16   = (f16*)(ws + 100663296);               // -> 117,440,512
    // [117,440,512 .. 134,217,728) dead
    bf16*     vt     = (bf16*)(ws + 134217728);              // -> 150,994,944
    uint16_t* counts = (uint16_t*)(ws + 150994944);          // -> 151,060,480
    const size_t need = 151060480;  // == R2-proven ws_size lower bound
    if (ws_size < need) return;

    proj_q16<<<256, 512, 0, stream>>>(x, wqk, qn32);
    proj_v16<<<dim3(128, 8), 256, 0, stream>>>(x, wv, vt);
    norm_q<<<4096, 256, 0, stream>>>(qn32, qh16);
    qk_mfma<<<256, 512, 0, stream>>>(qn32, qh16, counts, idxs, vals);
    pv_mfma<<<256, 512, 0, stream>>>(vt, counts, idxs, vals, gamma, beta, out);
}